// Round 7
// baseline (188.755 us; speedup 1.0000x reference)
//
#include <hip/hip_runtime.h>
#include <stdint.h>

#define A_N 65536
#define B_N 16
#define G_N 64
#define FEPS 1e-7f

#define NBIN 2048
#define SHB  21      // bin = keybits >> 21  (sign + 8 exp + 2 mantissa bits)
#define CAP  16384   // boundary-bin LDS capacity (64 KB); quarter-octave bins can hold ~10% of keys

// fast focal loss (tolerance path): 2 transcendentals + rcp, ~1e-6 rel err
__device__ __forceinline__ float focal_one(float l, float tt) {
  float e  = __expf(-fabsf(l));                    // e^{-|l|}
  float sp = __logf(1.0f + e);                     // log1p(e^{-|l|})
  bool  tp = tt > 0.5f;
  float ce = (tp ? fmaxf(-l, 0.0f) : fmaxf(l, 0.0f)) + sp;   // BCE-with-logits
  float inv = __builtin_amdgcn_rcpf(1.0f + e);     // 1/(1+e)
  float sig = (l >= 0.0f) ? inv : e * inv;         // sigmoid(l)
  float om  = tp ? (1.0f - sig) : sig;             // 1 - p_t
  om = fminf(fmaxf(om, FEPS), 1.0f - FEPS);        // == clamp of p_t reversed
  float alpha = tp ? 0.25f : 0.75f;
  return alpha * om * om * ce;
}

// DIoU loss for one (pred, gt) pair (tolerance path)
__device__ __forceinline__ float diou_one(float4 p, float4 q) {
  float ap = (p.z - p.x) * (p.w - p.y);
  float ag = (q.z - q.x) * (q.w - q.y);
  float ix1 = fmaxf(p.x, q.x), iy1 = fmaxf(p.y, q.y);
  float ix2 = fminf(p.z, q.z), iy2 = fminf(p.w, q.w);
  float iw = fmaxf(ix2 - ix1, 0.0f), ih = fmaxf(iy2 - iy1, 0.0f);
  float inter = iw * ih;
  float iou = inter / (ap + ag - inter + FEPS);
  float cpx = (p.x + p.z) * 0.5f, cpy = (p.y + p.w) * 0.5f;
  float cgx = (q.x + q.z) * 0.5f, cgy = (q.y + q.w) * 0.5f;
  float dx = cpx - cgx, dy = cpy - cgy;
  float cd2 = dx * dx + dy * dy;
  float ex1 = fminf(p.x, q.x), ey1 = fminf(p.y, q.y);
  float ex2 = fmaxf(p.z, q.z), ey2 = fmaxf(p.w, q.w);
  float ddx = ex2 - ex1, ddy = ey2 - ey1;
  float dg2 = ddx * ddx + ddy * ddy + FEPS;
  return 1.0f - iou + cd2 / dg2;   // LOC_LOSS_WEIGHT = 1
}

// ---------------- K0: zero global hist (cnt+sum contiguous, 65536 words) + done_ctr ----------------
__global__ void dl_init(uint32_t* __restrict__ histz, uint32_t* __restrict__ done_ctr) {
  int i = blockIdx.x * 1024 + threadIdx.x;
  histz[i] = 0u;
  if (i == 0) *done_ctr = 0u;
}

// ---------------- K1: matching (row argmax + rotating column argmax) FUSED with
// focal/negkey/DIoU/hist/partials — one pass over all anchors ----------------
__global__ __launch_bounds__(256) void dl_pass1(
    const float4* __restrict__ bbox, const float* __restrict__ conf,
    const float4* __restrict__ gt,
    uint8_t* __restrict__ best_idx, uint32_t* __restrict__ negkey,
    unsigned long long* __restrict__ gt_part,
    uint32_t* __restrict__ hist_cnt, float* __restrict__ hist_sum,
    float* __restrict__ part_loc, float* __restrict__ part_fl, float* __restrict__ part_np) {
  const int img = blockIdx.y;
  const int bx  = blockIdx.x;
  const int t   = threadIdx.x;
  const int wave = t >> 6, lane = t & 63;
  const int a = bx * 256 + t;
  const int idx = img * A_N + a;

  __shared__ float4 sg[G_N];
  __shared__ float  sga[G_N];
  __shared__ unsigned long long spart[4][G_N];
  __shared__ uint32_t hc[NBIN];
  __shared__ float    hs[NBIN];
  __shared__ float sl[4], sf[4], sn[4];

  for (int i = t; i < NBIN; i += 256) { hc[i] = 0u; hs[i] = 0.f; }
  if (t < G_N) {
    float4 q0 = gt[img * G_N + t];
    sg[t] = q0;
    // exact f32, no contraction (matches numpy bit-for-bit)
    sga[t] = __fmul_rn(__fsub_rn(q0.z, q0.x), __fsub_rn(q0.w, q0.y));
  }
  __syncthreads();

  float4 p = bbox[idx];
  float pa = __fmul_rn(__fsub_rn(p.z, p.x), __fsub_rn(p.w, p.y));
  float l = conf[idx];

  float bi = 0.f, bd = 1.f; int bidx = 0; float posm = -1.f;
  uint32_t colkey = 0u;                       // rotating column-max register
  const int rotsrc = (lane + 1) & 63;         // pull from next lane after each iter
  const uint32_t lanecomp = 63u - (uint32_t)lane;  // smaller lane wins ties under max

  int g = lane;
  #pragma unroll 4
  for (int j = 0; j < G_N; ++j) {
    float4 q = sg[g];
    float qa = sga[g];
    float ix1 = fmaxf(p.x, q.x), iy1 = fmaxf(p.y, q.y);
    float ix2 = fminf(p.z, q.z), iy2 = fminf(p.w, q.w);
    float iw = fmaxf(__fsub_rn(ix2, ix1), 0.f);
    float ih = fmaxf(__fsub_rn(iy2, iy1), 0.f);
    float inter = __fmul_rn(iw, ih);
    float den = __fadd_rn(__fsub_rn(__fadd_rn(pa, qa), inter), FEPS);  // exact numpy den
    // row argmax via cross-mult (no division); strict > keeps first-occurrence semantics
    if (inter * bd > bi * den) { bi = inter; bd = den; bidx = g; }
    // pos threshold EXACT: iou > 0.5 <=> sign(2*inter - den) > 0 (RN preserves sign)
    posm = fmaxf(posm, __fmaf_rn(2.f, inter, -den));
    // column candidate: approx ratio (1-ulp rcp), top 26 bits | lane-complement
    float ratio = inter * __builtin_amdgcn_rcpf(den);
    uint32_t key = (__float_as_uint(ratio) & 0xFFFFFFC0u) | lanecomp;
    if (key > colkey) colkey = key;
    colkey = __shfl(colkey, rotsrc);          // register now belongs to g+1
    g = (g + 1) & 63;
  }

  const bool pos = posm > 0.f;
  best_idx[idx] = (uint8_t)bidx;

  // ---- fused focal + negkey + DIoU (matched gt is already in LDS) ----
  float fl = focal_one(l, pos ? 1.0f : 0.0f);
  negkey[idx] = pos ? 0u : __float_as_uint(fl);  // fl > 0 strictly; 0 sentinel below all negatives
  float locv = pos ? diou_one(p, sg[bidx]) : 0.0f;
  if (!pos) {
    uint32_t kb = __float_as_uint(fl);
    atomicAdd(&hc[kb >> SHB], 1u);       // 256 keys into 2048 bins: ~conflict-free
    atomicAdd(&hs[kb >> SHB], fl);
  }

  // lane l holds the wave's column max for gt l; build cross-block comparable u64 key
  uint32_t winlane = 63u - (colkey & 63u);
  uint32_t ganchor = (uint32_t)(bx * 256 + wave * 64) + winlane;
  unsigned long long wkey = ((unsigned long long)(colkey & 0xFFFFFFC0u) << 32)
                          | (unsigned)~ganchor;  // smaller global idx wins ties
  spart[wave][lane] = wkey;

  // per-wave partials
  float flp = pos ? fl : 0.0f;
  float np1 = pos ? 1.0f : 0.0f;
  float lv = locv;
  for (int o = 32; o; o >>= 1) {
    lv  += __shfl_down(lv, o);
    flp += __shfl_down(flp, o);
    np1 += __shfl_down(np1, o);
  }
  if (lane == 0) { sl[wave] = lv; sf[wave] = flp; sn[wave] = np1; }
  __syncthreads();

  // flush nonzero hist bins (~60 hot bins/block), gt partial, block partials
  for (int i = t; i < NBIN; i += 256) {
    uint32_t c = hc[i];
    if (c) {
      atomicAdd(&hist_cnt[img * NBIN + i], c);
      atomicAdd(&hist_sum[img * NBIN + i], hs[i]);
    }
  }
  if (t < G_N) {
    unsigned long long m = spart[0][t];
    if (spart[1][t] > m) m = spart[1][t];
    if (spart[2][t] > m) m = spart[2][t];
    if (spart[3][t] > m) m = spart[3][t];
    gt_part[(((size_t)(img << 8) | bx) << 6) | t] = m;  // coalesced 512B store
  }
  if (t == 0) {
    const int pi = img * 256 + bx;
    part_loc[pi] = sl[0] + sl[1] + sl[2] + sl[3];
    part_fl[pi]  = sf[0] + sf[1] + sf[2] + sf[3];
    part_np[pi]  = sn[0] + sn[1] + sn[2] + sn[3];  // integer-valued, exact
  }
}

// ---------------- K2: force+fixup + partial reduce + exact top-k + finale ----------------
__global__ __launch_bounds__(1024) void dl_select(
    uint32_t* negkey,   // no __restrict__: aliased below
    const unsigned long long* __restrict__ gt_part,
    const uint32_t* __restrict__ hist_cnt, const float* __restrict__ hist_sum,
    const float* __restrict__ part_loc, const float* __restrict__ part_fl,
    const float* __restrict__ part_np,
    const float4* __restrict__ bbox, const float* __restrict__ conf,
    const float4* __restrict__ gt, const uint8_t* __restrict__ best_idx,
    float* __restrict__ acc, uint32_t* __restrict__ done_ctr, float* __restrict__ out) {
  const int img = blockIdx.x;
  const int t = threadIdx.x;
  const int lane = t & 63;
  uint32_t* negk = negkey + (size_t)img * A_N;
  const uint4* k4 = (const uint4*)negk;
  const int N4 = A_N / 4;  // 16384

  __shared__ uint32_t cnt[NBIN];
  __shared__ float    bsum[NBIN];
  __shared__ uint32_t cbuf[CAP];          // 64 KB
  __shared__ unsigned long long gred[16][G_N];
  __shared__ float s3[3][4];
  __shared__ float redf[16];
  __shared__ int   redi[16];
  __shared__ float np_sh, psum_sh, loc_sh, sstar_sh, negsum_sh;
  __shared__ float fix_l, fix_f, fix_n;
  __shared__ uint32_t bstar_sh, cstar_sh, ccnt_sh;

  // ---- region A: load hist, stage gt_part partial-max, reduce block partials ----
  for (int i = t; i < NBIN; i += 1024) {
    cnt[i]  = hist_cnt[img * NBIN + i];
    bsum[i] = hist_sum[img * NBIN + i];
  }
  {
    const int g = t & 63, ch = t >> 6;   // 16 chunks x 64 gts
    unsigned long long m = 0ull;
    #pragma unroll 4
    for (int j = 0; j < 16; ++j) {
      unsigned long long v = gt_part[(((size_t)(img << 8) | (ch * 16 + j)) << 6) | g];
      if (v > m) m = v;
    }
    gred[ch][g] = m;
  }
  float lv = 0.f, fv = 0.f, nv = 0.f;
  if (t < 256) {
    lv = part_loc[img * 256 + t];
    fv = part_fl[img * 256 + t];
    nv = part_np[img * 256 + t];
  }
  for (int o = 32; o; o >>= 1) {
    lv += __shfl_down(lv, o);
    fv += __shfl_down(fv, o);
    nv += __shfl_down(nv, o);
  }
  if (t < 256 && (t & 63) == 0) { s3[0][t >> 6] = lv; s3[1][t >> 6] = fv; s3[2][t >> 6] = nv; }
  __syncthreads();

  // ---- region B (wave 0): per-gt final argmax + forced-positive fixup ----
  if (t < 64) {
    unsigned long long m = gred[0][t];
    #pragma unroll
    for (int c = 1; c < 16; ++c) if (gred[c][t] > m) m = gred[c][t];
    // all-zero column: ratio bits 0 for every anchor -> max low-word = ~0 -> anchor 0 (numpy argmax)
    uint32_t a = ~(uint32_t)(m & 0xFFFFFFFFull);
    // dedupe multiple gts forcing the same anchor; also skips already-positive anchors
    uint32_t old = atomicExch(&negk[a], 0u);
    float dl = 0.f, df = 0.f, dn = 0.f;
    if (old != 0u) {
      dn = 1.f;
      float fln = __uint_as_float(old);
      uint32_t bin = old >> SHB;
      atomicSub(&cnt[bin], 1u);          // remove from negative hist
      atomicAdd(&bsum[bin], -fln);
      const int ai = img * A_N + (int)a;
      df = focal_one(conf[ai], 1.0f);    // now a positive
      dl = diou_one(bbox[ai], gt[img * G_N + best_idx[ai]]);
    }
    for (int o = 32; o; o >>= 1) {
      dl += __shfl_down(dl, o);
      df += __shfl_down(df, o);
      dn += __shfl_down(dn, o);
    }
    if (t == 0) { fix_l = dl; fix_f = df; fix_n = dn; }
  }
  __threadfence();
  __syncthreads();

  if (t == 0) {
    loc_sh  = s3[0][0] + s3[0][1] + s3[0][2] + s3[0][3] + fix_l;
    psum_sh = s3[1][0] + s3[1][1] + s3[1][2] + s3[1][3] + fix_f;
    np_sh   = s3[2][0] + s3[2][1] + s3[2][2] + s3[2][3] + fix_n;
    negsum_sh = 0.f;
  }
  __syncthreads();

  const int np = (int)(np_sh + 0.5f);
  const int k = min(A_N - np, 3 * np);

  if (k > 0) {
    // ---- wave 0: find threshold bin b*: C(b*) < k <= C(b*)+cnt[b*] ----
    if (t < 64) {
      const int CH = NBIN / 64;              // 32
      const int lob = NBIN - CH * (t + 1);   // lane 0 owns the TOP chunk
      uint32_t csum = 0;
      for (int b = lob; b < lob + CH; ++b) csum += cnt[b];
      uint32_t pre = csum;
      for (int o = 1; o < 64; o <<= 1) { uint32_t u = __shfl_up(pre, o); if (t >= o) pre += u; }
      uint32_t run = pre - csum;             // keys in bins above my chunk
      for (int b = lob + CH - 1; b >= lob; --b) {
        uint32_t c = cnt[b];
        if (run < (uint32_t)k && run + c >= (uint32_t)k) { bstar_sh = (uint32_t)b; cstar_sh = run; }
        run += c;
      }
    }
    __syncthreads();
    const int bstar = (int)bstar_sh;
    const uint32_t cstar = cstar_sh;
    const uint32_t cbin = cnt[bstar];
    const uint32_t r = (uint32_t)k - cstar;  // 1 <= r <= cbin

    // ---- Sstar = sum of all keys in bins > b* ----
    float s = 0.f;
    for (int i = t; i < NBIN; i += 1024) if (i > bstar) s += bsum[i];
    for (int o = 32; o; o >>= 1) s += __shfl_down(s, o);
    if ((t & 63) == 0) redf[t >> 6] = s;
    __syncthreads();
    if (t == 0) {
      float ss = 0.f;
      #pragma unroll
      for (int w = 0; w < 16; ++w) ss += redf[w];
      sstar_sh = ss;
    }
    __syncthreads();

    if (r == cbin) {
      if (t == 0) negsum_sh = sstar_sh + bsum[bstar];
    } else if (cbin <= (uint32_t)CAP) {
      // ---- ballot-compact boundary bin (1 LDS atomic per wave-iter), wave-0 bisect 21 bits ----
      if (t == 0) ccnt_sh = 0u;
      __syncthreads();
      for (int i = t; i < A_N; i += 1024) {
        uint32_t x = negk[i];
        bool mt = (x >> SHB) == (uint32_t)bstar;
        unsigned long long mask = __ballot(mt);
        uint32_t base = 0u;
        if (lane == 0) base = atomicAdd(&ccnt_sh, (uint32_t)__popcll(mask));
        base = __shfl(base, 0);
        if (mt) {
          uint32_t off = (uint32_t)__popcll(mask & ((1ull << lane) - 1ull));
          cbuf[base + off] = x;
        }
      }
      __syncthreads();
      if (t < 64) {
        const int n = (int)ccnt_sh;
        uint32_t lo = (uint32_t)bstar << SHB;
        uint32_t hi = ((uint32_t)bstar + 1u) << SHB;
        while (hi - lo > 1u) {
          uint32_t mid = lo + ((hi - lo) >> 1);
          int c = 0;
          for (int i = t; i < n; i += 64) c += (cbuf[i] >= mid) ? 1 : 0;
          for (int o = 32; o; o >>= 1) c += __shfl_down(c, o);
          c = __shfl(c, 0);
          if ((uint32_t)c >= r) lo = mid; else hi = mid;
        }
        float s2 = 0.f; int cg = 0;
        for (int i = t; i < n; i += 64) {
          uint32_t x = cbuf[i];
          if (x > lo) { s2 += __uint_as_float(x); cg++; }
        }
        for (int o = 32; o; o >>= 1) { s2 += __shfl_down(s2, o); cg += __shfl_down(cg, o); }
        if (t == 0) negsum_sh = sstar_sh + s2 + (float)(int)(r - (uint32_t)cg) * __uint_as_float(lo);
      }
    } else {
      // ---- fallback (adversarial giant tie bin): global bisection within the bin's range ----
      uint32_t lo = (uint32_t)bstar << SHB;
      uint32_t hi = ((uint32_t)bstar + 1u) << SHB;
      while (hi - lo > 1u) {
        uint32_t mid = lo + ((hi - lo) >> 1);
        int c = 0;
        for (int i = t; i < N4; i += 1024) {
          uint4 v = k4[i];
          c += (v.x >= mid) + (v.y >= mid) + (v.z >= mid) + (v.w >= mid);
        }
        for (int o = 32; o; o >>= 1) c += __shfl_down(c, o);
        if ((t & 63) == 0) redi[t >> 6] = c;
        __syncthreads();
        c = 0;
        #pragma unroll
        for (int w = 0; w < 16; ++w) c += redi[w];
        __syncthreads();
        if (c >= k) lo = mid; else hi = mid;
      }
      float s2 = 0.f; int cg = 0;
      for (int i = t; i < N4; i += 1024) {
        uint4 v = k4[i];
        if (v.x > lo) { s2 += __uint_as_float(v.x); cg++; }
        if (v.y > lo) { s2 += __uint_as_float(v.y); cg++; }
        if (v.z > lo) { s2 += __uint_as_float(v.z); cg++; }
        if (v.w > lo) { s2 += __uint_as_float(v.w); cg++; }
      }
      for (int o = 32; o; o >>= 1) { s2 += __shfl_down(s2, o); cg += __shfl_down(cg, o); }
      if ((t & 63) == 0) { redf[t >> 6] = s2; redi[t >> 6] = cg; }
      __syncthreads();
      if (t == 0) {
        float ss = 0.f; int cc = 0;
        #pragma unroll
        for (int w = 0; w < 16; ++w) { ss += redf[w]; cc += redi[w]; }
        negsum_sh = ss + (float)(k - cc) * __uint_as_float(lo);
      }
    }
  }
  __syncthreads();
  if (t == 0) {
    acc[img] = loc_sh;
    acc[32 + img] = (float)np;
    acc[48 + img] = (psum_sh + negsum_sh) / fmaxf((float)(np + k), 1.0f);
    // ---- last-block finale: fence + device-scope counter ----
    __threadfence();
    uint32_t old = atomicAdd(done_ctr, 1u);
    if (old == (uint32_t)(B_N - 1)) {
      __threadfence();
      float sl = 0.f, sc = 0.f, sn = 0.f;
      for (int i = 0; i < B_N; ++i) {
        sl += acc[i];
        sc += acc[48 + i];
        sn += acc[32 + i];
      }
      float tp = fmaxf(sn, 1.0f);
      float al = sl / tp;
      float ac = sc / tp;
      out[0] = al + ac;
      out[1] = ac;
      out[2] = al;
    }
  }
}

extern "C" void kernel_launch(void* const* d_in, const int* in_sizes, int n_in,
                              void* d_out, int out_size, void* d_ws, size_t ws_size,
                              hipStream_t stream) {
  (void)in_sizes; (void)n_in; (void)out_size; (void)ws_size;

  const float4* bbox = (const float4*)d_in[0];   // [B, A, 4] f32
  const float*  conf = (const float*)d_in[1];    // [B, A] f32
  const float4* gt   = (const float4*)d_in[2];   // [B, G, 4] f32
  float* out = (float*)d_out;

  char* ws = (char*)d_ws;
  uint32_t*           negkey   = (uint32_t*)(ws);                       // 4 MiB
  unsigned long long* gt_part  = (unsigned long long*)(ws + (4u << 20));// 2 MiB [16][256][64]
  uint8_t*            best_idx = (uint8_t*)(ws + (6u << 20));          // 1 MiB
  char* hb = ws + (7u << 20);
  uint32_t* hist_cnt = (uint32_t*)(hb);                                // 128 KiB [16][2048]
  float*    hist_sum = (float*)(hb + (size_t)B_N * NBIN * 4);          // 128 KiB (contiguous after cnt)
  char* tail = hb + 2 * (size_t)B_N * NBIN * 4;
  float* part_loc = (float*)(tail);                                    // 16 KiB
  float* part_fl  = (float*)(tail + 16384);
  float* part_np  = (float*)(tail + 32768);
  float* acc      = (float*)(tail + 49152);                            // 64 floats
  uint32_t* done_ctr = (uint32_t*)(tail + 49152 + 256);

  dl_init<<<64, 1024, 0, stream>>>(hist_cnt /* zeroes cnt+sum (contiguous) */, done_ctr);
  dl_pass1<<<dim3(A_N / 256, B_N), 256, 0, stream>>>(bbox, conf, gt, best_idx, negkey,
                                                     gt_part, hist_cnt, hist_sum,
                                                     part_loc, part_fl, part_np);
  dl_select<<<B_N, 1024, 0, stream>>>(negkey, gt_part, hist_cnt, hist_sum,
                                      part_loc, part_fl, part_np,
                                      bbox, conf, gt, best_idx, acc, done_ctr, out);
}

// Round 8
// 155.324 us; speedup vs baseline: 1.2152x; 1.2152x over previous
//
#include <hip/hip_runtime.h>
#include <stdint.h>

#define A_N 65536
#define B_N 16
#define G_N 64
#define FEPS 1e-7f

#define NBIN 2048
#define SHB  21      // L1 bin = keybits >> 21 (sign + 8 exp + 2 mantissa bits)
#define CAP  8192    // boundary-bin LDS capacity (32 KB)

// fast focal loss (tolerance path): 2 transcendentals + rcp, ~1e-6 rel err
__device__ __forceinline__ float focal_one(float l, float tt) {
  float e  = __expf(-fabsf(l));                    // e^{-|l|}
  float sp = __logf(1.0f + e);                     // log1p(e^{-|l|})
  bool  tp = tt > 0.5f;
  float ce = (tp ? fmaxf(-l, 0.0f) : fmaxf(l, 0.0f)) + sp;   // BCE-with-logits
  float inv = __builtin_amdgcn_rcpf(1.0f + e);     // 1/(1+e)
  float sig = (l >= 0.0f) ? inv : e * inv;         // sigmoid(l)
  float om  = tp ? (1.0f - sig) : sig;             // 1 - p_t
  om = fminf(fmaxf(om, FEPS), 1.0f - FEPS);
  float alpha = tp ? 0.25f : 0.75f;
  return alpha * om * om * ce;
}

// DIoU loss for one (pred, gt) pair (tolerance path)
__device__ __forceinline__ float diou_one(float4 p, float4 q) {
  float ap = (p.z - p.x) * (p.w - p.y);
  float ag = (q.z - q.x) * (q.w - q.y);
  float ix1 = fmaxf(p.x, q.x), iy1 = fmaxf(p.y, q.y);
  float ix2 = fminf(p.z, q.z), iy2 = fminf(p.w, q.w);
  float iw = fmaxf(ix2 - ix1, 0.0f), ih = fmaxf(iy2 - iy1, 0.0f);
  float inter = iw * ih;
  float iou = inter / (ap + ag - inter + FEPS);
  float cpx = (p.x + p.z) * 0.5f, cpy = (p.y + p.w) * 0.5f;
  float cgx = (q.x + q.z) * 0.5f, cgy = (q.y + q.w) * 0.5f;
  float dx = cpx - cgx, dy = cpy - cgy;
  float cd2 = dx * dx + dy * dy;
  float ex1 = fminf(p.x, q.x), ey1 = fminf(p.y, q.y);
  float ex2 = fmaxf(p.z, q.z), ey2 = fmaxf(p.w, q.w);
  float ddx = ex2 - ex1, ddy = ey2 - ey1;
  float dg2 = ddx * ddx + ddy * ddy + FEPS;
  return 1.0f - iou + cd2 / dg2;   // LOC_LOSS_WEIGHT = 1
}

// ---------------- K0: zero global hist (cnt+sum contiguous, 65536 words) + done_ctr ----------------
__global__ void dl_init(uint32_t* __restrict__ histz, uint32_t* __restrict__ done_ctr) {
  int i = blockIdx.x * 1024 + threadIdx.x;
  histz[i] = 0u;
  if (i == 0) *done_ctr = 0u;
}

// ---------------- K1: matching (packed-key row argmax + rotating column argmax) FUSED with
// focal/negkey/DIoU/hist/partials — one pass over all anchors ----------------
__global__ __launch_bounds__(256) void dl_pass1(
    const float4* __restrict__ bbox, const float* __restrict__ conf,
    const float4* __restrict__ gt,
    uint8_t* __restrict__ best_idx, uint32_t* __restrict__ negkey,
    unsigned long long* __restrict__ gt_part,
    uint32_t* __restrict__ hist_cnt, float* __restrict__ hist_sum,
    float* __restrict__ part_loc, float* __restrict__ part_fl, float* __restrict__ part_np) {
  const int img = blockIdx.y;
  const int bx  = blockIdx.x;
  const int t   = threadIdx.x;
  const int wave = t >> 6, lane = t & 63;
  const int a = bx * 256 + t;
  const int idx = img * A_N + a;

  __shared__ float4 sg[G_N];
  __shared__ float  sga[G_N];
  __shared__ unsigned long long spart[4][G_N];
  __shared__ uint32_t hc[NBIN];
  __shared__ float    hs[NBIN];
  __shared__ float sl[4], sf[4], sn[4];

  for (int i = t; i < NBIN; i += 256) { hc[i] = 0u; hs[i] = 0.f; }
  if (t < G_N) {
    float4 q0 = gt[img * G_N + t];
    sg[t] = q0;
    // exact f32, no contraction (matches numpy bit-for-bit)
    sga[t] = __fmul_rn(__fsub_rn(q0.z, q0.x), __fsub_rn(q0.w, q0.y));
  }
  __syncthreads();

  float4 p = bbox[idx];
  float pa = __fmul_rn(__fsub_rn(p.z, p.x), __fsub_rn(p.w, p.y));
  float l = conf[idx];

  float posm = -1.f;
  uint32_t rowkey = 0u;                       // packed (ratio_bits | 63-g) row max
  uint32_t colkey = 0u;                       // rotating column-max register
  const int rotsrc = (lane + 1) & 63;         // pull from next lane after each iter
  const uint32_t lanecomp = 63u - (uint32_t)lane;  // smaller lane wins ties under max

  int g = lane;
  #pragma unroll 4
  for (int j = 0; j < G_N; ++j) {
    float4 q = sg[g];
    float qa = sga[g];
    float ix1 = fmaxf(p.x, q.x), iy1 = fmaxf(p.y, q.y);
    float ix2 = fminf(p.z, q.z), iy2 = fminf(p.w, q.w);
    float iw = fmaxf(__fsub_rn(ix2, ix1), 0.f);
    float ih = fmaxf(__fsub_rn(iy2, iy1), 0.f);
    float inter = __fmul_rn(iw, ih);
    float den = __fadd_rn(__fsub_rn(__fadd_rn(pa, qa), inter), FEPS);  // exact numpy den
    // pos threshold EXACT: iou > 0.5 <=> sign(2*inter - den) > 0 (RN preserves sign)
    posm = fmaxf(posm, __fmaf_rn(2.f, inter, -den));
    // shared approx ratio (1-ulp rcp); near-tie flips are measure-zero on random data
    float ratio = inter * __builtin_amdgcn_rcpf(den);
    uint32_t base = __float_as_uint(ratio) & 0xFFFFFFC0u;
    uint32_t rkey = base | (63u - (uint32_t)g);   // smaller g wins ties (first occurrence)
    if (rkey > rowkey) rowkey = rkey;
    uint32_t ckey = base | lanecomp;
    if (ckey > colkey) colkey = ckey;
    colkey = __shfl(colkey, rotsrc);          // register now belongs to g+1
    g = (g + 1) & 63;
  }

  const bool pos = posm > 0.f;
  const int bidx = 63 - (int)(rowkey & 63u);
  best_idx[idx] = (uint8_t)bidx;

  // ---- fused focal + negkey + DIoU (matched gt is already in LDS) ----
  float fl = focal_one(l, pos ? 1.0f : 0.0f);
  negkey[idx] = pos ? 0u : __float_as_uint(fl);  // fl > 0 strictly; 0 sentinel below all negatives
  float locv = pos ? diou_one(p, sg[bidx]) : 0.0f;
  if (!pos) {
    uint32_t kb = __float_as_uint(fl);
    atomicAdd(&hc[kb >> SHB], 1u);       // 256 keys into 2048 bins: ~conflict-free
    atomicAdd(&hs[kb >> SHB], fl);
  }

  // lane l holds the wave's column max for gt l; build cross-block comparable u64 key
  uint32_t winlane = 63u - (colkey & 63u);
  uint32_t ganchor = (uint32_t)(bx * 256 + wave * 64) + winlane;
  unsigned long long wkey = ((unsigned long long)(colkey & 0xFFFFFFC0u) << 32)
                          | (unsigned)~ganchor;  // smaller global idx wins ties
  spart[wave][lane] = wkey;

  // per-wave partials
  float flp = pos ? fl : 0.0f;
  float np1 = pos ? 1.0f : 0.0f;
  float lv = locv;
  for (int o = 32; o; o >>= 1) {
    lv  += __shfl_down(lv, o);
    flp += __shfl_down(flp, o);
    np1 += __shfl_down(np1, o);
  }
  if (lane == 0) { sl[wave] = lv; sf[wave] = flp; sn[wave] = np1; }
  __syncthreads();

  // flush nonzero hist bins, gt partial, block partials
  for (int i = t; i < NBIN; i += 256) {
    uint32_t c = hc[i];
    if (c) {
      atomicAdd(&hist_cnt[img * NBIN + i], c);
      atomicAdd(&hist_sum[img * NBIN + i], hs[i]);
    }
  }
  if (t < G_N) {
    unsigned long long m = spart[0][t];
    if (spart[1][t] > m) m = spart[1][t];
    if (spart[2][t] > m) m = spart[2][t];
    if (spart[3][t] > m) m = spart[3][t];
    gt_part[(((size_t)(img << 8) | bx) << 6) | t] = m;  // coalesced 512B store
  }
  if (t == 0) {
    const int pi = img * 256 + bx;
    part_loc[pi] = sl[0] + sl[1] + sl[2] + sl[3];
    part_fl[pi]  = sf[0] + sf[1] + sf[2] + sf[3];
    part_np[pi]  = sn[0] + sn[1] + sn[2] + sn[3];  // integer-valued, exact
  }
}

// ---------------- K2: force+fixup + radix-histogram top-k (no bisect, no serial chains) ----------------
__global__ __launch_bounds__(1024) void dl_select(
    uint32_t* negkey,   // no __restrict__: read after in-kernel atomicExch fixup
    const unsigned long long* __restrict__ gt_part,
    const uint32_t* __restrict__ hist_cnt, const float* __restrict__ hist_sum,
    const float* __restrict__ part_loc, const float* __restrict__ part_fl,
    const float* __restrict__ part_np,
    const float4* __restrict__ bbox, const float* __restrict__ conf,
    const float4* __restrict__ gt, const uint8_t* __restrict__ best_idx,
    float* __restrict__ acc, uint32_t* __restrict__ done_ctr, float* __restrict__ out) {
  const int img = blockIdx.x;
  const int t = threadIdx.x;
  uint32_t* negk = negkey + (size_t)img * A_N;
  const uint4* k4 = (const uint4*)negk;
  const int N4 = A_N / 4;  // 16384

  __shared__ uint32_t cnt[NBIN];     // L1: bits[31:21]
  __shared__ float    bsum[NBIN];
  __shared__ uint32_t hc2[NBIN];     // L2: bits[20:10]
  __shared__ float    hs2[NBIN];
  __shared__ uint32_t cnt3[1024];    // L3: bits[9:0] (exact values)
  __shared__ uint32_t cbuf[CAP];     // 32 KB boundary-bin keys
  __shared__ unsigned long long gred[16][G_N];
  __shared__ float s3[3][4];
  __shared__ float redf[16];
  __shared__ float np_sh, psum_sh, loc_sh, sstar_sh, sstar2_sh, negsum_sh;
  __shared__ float fix_l, fix_f, fix_n;
  __shared__ uint32_t bstar_sh, cstar_sh, b2_sh, c2_sh, j3_sh, c3_sh, ccnt_sh;

  // ---- region A: load L1 hist, zero L2/L3, stage gt_part, reduce block partials ----
  for (int i = t; i < NBIN; i += 1024) {
    cnt[i]  = hist_cnt[img * NBIN + i];
    bsum[i] = hist_sum[img * NBIN + i];
    hc2[i] = 0u; hs2[i] = 0.f;
  }
  if (t < 1024) cnt3[t] = 0u;
  if (t == 0) ccnt_sh = 0u;
  {
    const int g = t & 63, ch = t >> 6;   // 16 chunks x 64 gts
    unsigned long long m = 0ull;
    #pragma unroll 4
    for (int j = 0; j < 16; ++j) {
      unsigned long long v = gt_part[(((size_t)(img << 8) | (ch * 16 + j)) << 6) | g];
      if (v > m) m = v;
    }
    gred[ch][g] = m;
  }
  float lv = 0.f, fv = 0.f, nv = 0.f;
  if (t < 256) {
    lv = part_loc[img * 256 + t];
    fv = part_fl[img * 256 + t];
    nv = part_np[img * 256 + t];
  }
  for (int o = 32; o; o >>= 1) {
    lv += __shfl_down(lv, o);
    fv += __shfl_down(fv, o);
    nv += __shfl_down(nv, o);
  }
  if (t < 256 && (t & 63) == 0) { s3[0][t >> 6] = lv; s3[1][t >> 6] = fv; s3[2][t >> 6] = nv; }
  __syncthreads();

  // ---- region B (wave 0): per-gt final argmax + forced-positive fixup ----
  if (t < 64) {
    unsigned long long m = gred[0][t];
    #pragma unroll
    for (int c = 1; c < 16; ++c) if (gred[c][t] > m) m = gred[c][t];
    // all-zero column: ratio bits 0 -> max low-word = ~0 -> anchor 0 (numpy argmax)
    uint32_t a = ~(uint32_t)(m & 0xFFFFFFFFull);
    // dedupe multiple gts forcing the same anchor; skips already-positive anchors
    uint32_t old = atomicExch(&negk[a], 0u);
    float dl = 0.f, df = 0.f, dn = 0.f;
    if (old != 0u) {
      dn = 1.f;
      float fln = __uint_as_float(old);
      uint32_t bin = old >> SHB;
      atomicSub(&cnt[bin], 1u);          // remove from negative hist
      atomicAdd(&bsum[bin], -fln);
      const int ai = img * A_N + (int)a;
      df = focal_one(conf[ai], 1.0f);    // now a positive
      dl = diou_one(bbox[ai], gt[img * G_N + best_idx[ai]]);
    }
    for (int o = 32; o; o >>= 1) {
      dl += __shfl_down(dl, o);
      df += __shfl_down(df, o);
      dn += __shfl_down(dn, o);
    }
    if (t == 0) { fix_l = dl; fix_f = df; fix_n = dn; }
  }
  __threadfence();
  __syncthreads();

  if (t == 0) {
    loc_sh  = s3[0][0] + s3[0][1] + s3[0][2] + s3[0][3] + fix_l;
    psum_sh = s3[1][0] + s3[1][1] + s3[1][2] + s3[1][3] + fix_f;
    np_sh   = s3[2][0] + s3[2][1] + s3[2][2] + s3[2][3] + fix_n;
    negsum_sh = 0.f;
  }
  __syncthreads();

  const int np = (int)(np_sh + 0.5f);
  const int k = min(A_N - np, 3 * np);

  if (k > 0) {
    // ---- L1 scan (wave 0): threshold bin b*: C(>b*) < k <= C(>=b*) ----
    if (t < 64) {
      const int CH = NBIN / 64;
      const int lob = NBIN - CH * (t + 1);   // lane 0 owns the TOP chunk
      uint32_t csum = 0;
      for (int b = lob; b < lob + CH; ++b) csum += cnt[b];
      uint32_t pre = csum;
      for (int o = 1; o < 64; o <<= 1) { uint32_t u = __shfl_up(pre, o); if (t >= o) pre += u; }
      uint32_t run = pre - csum;
      for (int b = lob + CH - 1; b >= lob; --b) {
        uint32_t c = cnt[b];
        if (run < (uint32_t)k && run + c >= (uint32_t)k) { bstar_sh = (uint32_t)b; cstar_sh = run; }
        run += c;
      }
    }
    __syncthreads();
    const uint32_t bstar = bstar_sh;
    const uint32_t cbin = cnt[bstar];
    const uint32_t r = (uint32_t)k - cstar_sh;  // 1 <= r <= cbin

    // ---- Sstar = sum of keys in L1 bins > b* (all threads) ----
    float s = 0.f;
    for (int i = t; i < NBIN; i += 1024) if (i > (int)bstar) s += bsum[i];
    for (int o = 32; o; o >>= 1) s += __shfl_down(s, o);
    if ((t & 63) == 0) redf[t >> 6] = s;
    __syncthreads();
    if (t == 0) {
      float ss = 0.f;
      #pragma unroll
      for (int w = 0; w < 16; ++w) ss += redf[w];
      sstar_sh = ss;
    }
    __syncthreads();

    if (r == cbin) {
      if (t == 0) negsum_sh = sstar_sh + bsum[bstar];
    } else {
      // ---- one uint4 streaming pass: compact boundary-bin keys + build L2 hist ----
      // (independent loads -> MLP; LDS atomics only for ~cbin matches; skip x==0 positives)
      for (int i = t; i < N4; i += 1024) {
        uint4 v = k4[i];
        #pragma unroll
        for (int c = 0; c < 4; ++c) {
          uint32_t x = (c == 0) ? v.x : (c == 1) ? v.y : (c == 2) ? v.z : v.w;
          if (x != 0u && (x >> SHB) == bstar) {
            uint32_t slot = atomicAdd(&ccnt_sh, 1u);
            if (slot < (uint32_t)CAP) cbuf[slot] = x;
            atomicAdd(&hc2[(x >> 10) & 2047u], 1u);
            atomicAdd(&hs2[(x >> 10) & 2047u], __uint_as_float(x));
          }
        }
      }
      __syncthreads();

      // ---- L2 scan (wave 0): sub-bin b2*: C2(>b2*) < r <= C2(>=b2*) ----
      if (t < 64) {
        const int CH = NBIN / 64;
        const int lob = NBIN - CH * (t + 1);
        uint32_t csum = 0;
        for (int b = lob; b < lob + CH; ++b) csum += hc2[b];
        uint32_t pre = csum;
        for (int o = 1; o < 64; o <<= 1) { uint32_t u = __shfl_up(pre, o); if (t >= o) pre += u; }
        uint32_t run = pre - csum;
        for (int b = lob + CH - 1; b >= lob; --b) {
          uint32_t c = hc2[b];
          if (run < r && run + c >= r) { b2_sh = (uint32_t)b; c2_sh = run; }
          run += c;
        }
      }
      __syncthreads();
      const uint32_t b2 = b2_sh;
      const uint32_t cbin2 = hc2[b2];
      const uint32_t r3 = r - c2_sh;  // 1 <= r3 <= cbin2

      // ---- Sstar2 = sum of keys in L2 bins > b2* (all threads) ----
      float s2 = 0.f;
      for (int i = t; i < NBIN; i += 1024) if (i > (int)b2) s2 += hs2[i];
      for (int o = 32; o; o >>= 1) s2 += __shfl_down(s2, o);
      if ((t & 63) == 0) redf[t >> 6] = s2;
      __syncthreads();
      if (t == 0) {
        float ss = 0.f;
        #pragma unroll
        for (int w = 0; w < 16; ++w) ss += redf[w];
        sstar2_sh = ss;
      }
      __syncthreads();

      if (r3 == cbin2) {
        if (t == 0) negsum_sh = sstar_sh + sstar2_sh + hs2[b2];
      } else {
        // ---- L3: exact value histogram of sub-bin b2* (bits[9:0]) ----
        if (cbin <= (uint32_t)CAP) {
          const int n = (int)cbin;
          for (int i = t; i < n; i += 1024) {
            uint32_t x = cbuf[i];
            if (((x >> 10) & 2047u) == b2) atomicAdd(&cnt3[x & 1023u], 1u);
          }
        } else {
          // adversarial giant bin: re-stream, match top-22 bits
          const uint32_t top22 = (bstar << 11) | b2;
          for (int i = t; i < N4; i += 1024) {
            uint4 v = k4[i];
            if (v.x != 0u && (v.x >> 10) == top22) atomicAdd(&cnt3[v.x & 1023u], 1u);
            if (v.y != 0u && (v.y >> 10) == top22) atomicAdd(&cnt3[v.y & 1023u], 1u);
            if (v.z != 0u && (v.z >> 10) == top22) atomicAdd(&cnt3[v.z & 1023u], 1u);
            if (v.w != 0u && (v.w >> 10) == top22) atomicAdd(&cnt3[v.w & 1023u], 1u);
          }
        }
        __syncthreads();

        // ---- L3 scan (wave 0): exact value j*: C3(>j*) < r3 <= C3(>=j*) ----
        if (t < 64) {
          const int CH = 1024 / 64;  // 16
          const int lob = 1024 - CH * (t + 1);
          uint32_t csum = 0;
          for (int b = lob; b < lob + CH; ++b) csum += cnt3[b];
          uint32_t pre = csum;
          for (int o = 1; o < 64; o <<= 1) { uint32_t u = __shfl_up(pre, o); if (t >= o) pre += u; }
          uint32_t run = pre - csum;
          for (int b = lob + CH - 1; b >= lob; --b) {
            uint32_t c = cnt3[b];
            if (run < r3 && run + c >= r3) { j3_sh = (uint32_t)b; c3_sh = run; }
            run += c;
          }
        }
        __syncthreads();
        const uint32_t j3 = j3_sh;
        const uint32_t hibits = (bstar << SHB) | (b2 << 10);

        // ---- exact tail sum: bins above j* + boundary copies of val(j*) ----
        float s3v = 0.f;
        if (t < 1024 && t > (int)j3 && cnt3[t]) {
          s3v = (float)cnt3[t] * __uint_as_float(hibits | (uint32_t)t);
        }
        for (int o = 32; o; o >>= 1) s3v += __shfl_down(s3v, o);
        if ((t & 63) == 0) redf[t >> 6] = s3v;
        __syncthreads();
        if (t == 0) {
          float ss = 0.f;
          #pragma unroll
          for (int w = 0; w < 16; ++w) ss += redf[w];
          negsum_sh = sstar_sh + sstar2_sh + ss
                    + (float)(int)(r3 - c3_sh) * __uint_as_float(hibits | j3);
        }
      }
    }
  }
  __syncthreads();
  if (t == 0) {
    acc[img] = loc_sh;
    acc[32 + img] = (float)np;
    acc[48 + img] = (psum_sh + negsum_sh) / fmaxf((float)(np + k), 1.0f);
    // ---- last-block finale: fence + device-scope counter ----
    __threadfence();
    uint32_t old = atomicAdd(done_ctr, 1u);
    if (old == (uint32_t)(B_N - 1)) {
      __threadfence();
      float sl = 0.f, sc = 0.f, sn = 0.f;
      for (int i = 0; i < B_N; ++i) {
        sl += acc[i];
        sc += acc[48 + i];
        sn += acc[32 + i];
      }
      float tp = fmaxf(sn, 1.0f);
      float al = sl / tp;
      float ac = sc / tp;
      out[0] = al + ac;
      out[1] = ac;
      out[2] = al;
    }
  }
}

extern "C" void kernel_launch(void* const* d_in, const int* in_sizes, int n_in,
                              void* d_out, int out_size, void* d_ws, size_t ws_size,
                              hipStream_t stream) {
  (void)in_sizes; (void)n_in; (void)out_size; (void)ws_size;

  const float4* bbox = (const float4*)d_in[0];   // [B, A, 4] f32
  const float*  conf = (const float*)d_in[1];    // [B, A] f32
  const float4* gt   = (const float4*)d_in[2];   // [B, G, 4] f32
  float* out = (float*)d_out;

  char* ws = (char*)d_ws;
  uint32_t*           negkey   = (uint32_t*)(ws);                       // 4 MiB
  unsigned long long* gt_part  = (unsigned long long*)(ws + (4u << 20));// 2 MiB [16][256][64]
  uint8_t*            best_idx = (uint8_t*)(ws + (6u << 20));          // 1 MiB
  char* hb = ws + (7u << 20);
  uint32_t* hist_cnt = (uint32_t*)(hb);                                // 128 KiB [16][2048]
  float*    hist_sum = (float*)(hb + (size_t)B_N * NBIN * 4);          // 128 KiB (contiguous)
  char* tail = hb + 2 * (size_t)B_N * NBIN * 4;
  float* part_loc = (float*)(tail);                                    // 16 KiB
  float* part_fl  = (float*)(tail + 16384);
  float* part_np  = (float*)(tail + 32768);
  float* acc      = (float*)(tail + 49152);                            // 64 floats
  uint32_t* done_ctr = (uint32_t*)(tail + 49152 + 256);

  dl_init<<<64, 1024, 0, stream>>>(hist_cnt /* zeroes cnt+sum (contiguous) */, done_ctr);
  dl_pass1<<<dim3(A_N / 256, B_N), 256, 0, stream>>>(bbox, conf, gt, best_idx, negkey,
                                                     gt_part, hist_cnt, hist_sum,
                                                     part_loc, part_fl, part_np);
  dl_select<<<B_N, 1024, 0, stream>>>(negkey, gt_part, hist_cnt, hist_sum,
                                      part_loc, part_fl, part_np,
                                      bbox, conf, gt, best_idx, acc, done_ctr, out);
}

// Round 9
// 150.694 us; speedup vs baseline: 1.2526x; 1.0307x over previous
//
#include <hip/hip_runtime.h>
#include <stdint.h>

#define A_N 65536
#define B_N 16
#define G_N 64
#define FEPS 1e-7f

#define NBIN 2048
#define SHB  21      // L1 bin = keybits >> 21 (sign + 8 exp + 2 mantissa bits)

// fast focal loss (tolerance path): 2 transcendentals + rcp, ~1e-6 rel err
__device__ __forceinline__ float focal_one(float l, float tt) {
  float e  = __expf(-fabsf(l));                    // e^{-|l|}
  float sp = __logf(1.0f + e);                     // log1p(e^{-|l|})
  bool  tp = tt > 0.5f;
  float ce = (tp ? fmaxf(-l, 0.0f) : fmaxf(l, 0.0f)) + sp;   // BCE-with-logits
  float inv = __builtin_amdgcn_rcpf(1.0f + e);     // 1/(1+e)
  float sig = (l >= 0.0f) ? inv : e * inv;         // sigmoid(l)
  float om  = tp ? (1.0f - sig) : sig;             // 1 - p_t
  om = fminf(fmaxf(om, FEPS), 1.0f - FEPS);
  float alpha = tp ? 0.25f : 0.75f;
  return alpha * om * om * ce;
}

// DIoU loss for one (pred, gt) pair (tolerance path)
__device__ __forceinline__ float diou_one(float4 p, float4 q) {
  float ap = (p.z - p.x) * (p.w - p.y);
  float ag = (q.z - q.x) * (q.w - q.y);
  float ix1 = fmaxf(p.x, q.x), iy1 = fmaxf(p.y, q.y);
  float ix2 = fminf(p.z, q.z), iy2 = fminf(p.w, q.w);
  float iw = fmaxf(ix2 - ix1, 0.0f), ih = fmaxf(iy2 - iy1, 0.0f);
  float inter = iw * ih;
  float iou = inter / (ap + ag - inter + FEPS);
  float cpx = (p.x + p.z) * 0.5f, cpy = (p.y + p.w) * 0.5f;
  float cgx = (q.x + q.z) * 0.5f, cgy = (q.y + q.w) * 0.5f;
  float dx = cpx - cgx, dy = cpy - cgy;
  float cd2 = dx * dx + dy * dy;
  float ex1 = fminf(p.x, q.x), ey1 = fminf(p.y, q.y);
  float ex2 = fmaxf(p.z, q.z), ey2 = fmaxf(p.w, q.w);
  float ddx = ex2 - ex1, ddy = ey2 - ey1;
  float dg2 = ddx * ddx + ddy * ddy + FEPS;
  return 1.0f - iou + cd2 / dg2;   // LOC_LOSS_WEIGHT = 1
}

// ---------------- K0: zero global hist (cnt+sum contiguous, 65536 words) + done_ctr ----------------
__global__ void dl_init(uint32_t* __restrict__ histz, uint32_t* __restrict__ done_ctr) {
  int i = blockIdx.x * 1024 + threadIdx.x;
  histz[i] = 0u;
  if (i == 0) *done_ctr = 0u;
}

// ---------------- K1: matching (packed-key row argmax + rotating column argmax) FUSED with
// focal/negkey/DIoU/hist/partials — one pass over all anchors ----------------
__global__ __launch_bounds__(256) void dl_pass1(
    const float4* __restrict__ bbox, const float* __restrict__ conf,
    const float4* __restrict__ gt,
    uint8_t* __restrict__ best_idx, uint32_t* __restrict__ negkey,
    unsigned long long* __restrict__ gt_part,
    uint32_t* __restrict__ hist_cnt, float* __restrict__ hist_sum,
    float* __restrict__ part_loc, float* __restrict__ part_fl, float* __restrict__ part_np) {
  const int img = blockIdx.y;
  const int bx  = blockIdx.x;
  const int t   = threadIdx.x;
  const int wave = t >> 6, lane = t & 63;
  const int a = bx * 256 + t;
  const int idx = img * A_N + a;

  __shared__ float4 sg2[2 * G_N];   // gt boxes doubled: index lane+j needs no &63 wrap
  __shared__ float  sga2[2 * G_N];
  __shared__ unsigned long long spart[4][G_N];
  __shared__ uint32_t hc[NBIN];
  __shared__ float    hs[NBIN];
  __shared__ float sl[4], sf[4], sn[4];

  for (int i = t; i < NBIN; i += 256) { hc[i] = 0u; hs[i] = 0.f; }
  if (t < G_N) {
    float4 q0 = gt[img * G_N + t];
    // exact f32, no contraction (matches numpy bit-for-bit)
    float qa0 = __fmul_rn(__fsub_rn(q0.z, q0.x), __fsub_rn(q0.w, q0.y));
    sg2[t] = q0;  sg2[t + G_N] = q0;
    sga2[t] = qa0; sga2[t + G_N] = qa0;
  }
  __syncthreads();

  float4 p = bbox[idx];
  float pa = __fmul_rn(__fsub_rn(p.z, p.x), __fsub_rn(p.w, p.y));
  float l = conf[idx];

  float posm = -1.f;
  uint32_t rowkey = 0u;                       // packed (ratio_bits | 63-g) row max
  uint32_t colkey = 0u;                       // rotating column-max register
  uint32_t tb = 63u - (uint32_t)lane;         // rotating row tie-break = 63-g, g=(lane+j)&63
  const int rotsrc = (lane + 1) & 63;         // pull from next lane after each iter
  const uint32_t lanecomp = 63u - (uint32_t)lane;  // column tie-break (smaller lane wins)

  #pragma unroll 8
  for (int j = 0; j < G_N; ++j) {
    float4 q = sg2[lane + j];                 // fixed addr reg + offset:j*16 (2-way alias, free)
    float qa = sga2[lane + j];
    float ix1 = fmaxf(p.x, q.x), iy1 = fmaxf(p.y, q.y);
    float ix2 = fminf(p.z, q.z), iy2 = fminf(p.w, q.w);
    float iw = fmaxf(__fsub_rn(ix2, ix1), 0.f);
    float ih = fmaxf(__fsub_rn(iy2, iy1), 0.f);
    float inter = __fmul_rn(iw, ih);
    float den = __fadd_rn(__fsub_rn(__fadd_rn(pa, qa), inter), FEPS);  // exact numpy den
    // pos threshold EXACT: iou > 0.5 <=> sign(2*inter - den) > 0 (RN preserves sign)
    posm = fmaxf(posm, __fmaf_rn(2.f, inter, -den));
    // shared approx ratio (1-ulp rcp); near-tie flips are measure-zero on random data
    float ratio = inter * __builtin_amdgcn_rcpf(den);
    uint32_t base = __float_as_uint(ratio) & 0xFFFFFFC0u;
    uint32_t rkey = base | tb;                // smaller g wins ties (first occurrence)
    if (rkey > rowkey) rowkey = rkey;
    uint32_t ckey = base | lanecomp;
    if (ckey > colkey) colkey = ckey;
    colkey = __shfl(colkey, rotsrc);          // register now belongs to g+1
    tb = (tb - 1u) & 63u;                     // g+1 -> tie-break decrements (wraps 0->63)
  }

  const bool pos = posm > 0.f;
  const int bidx = 63 - (int)(rowkey & 63u);
  best_idx[idx] = (uint8_t)bidx;

  // ---- fused focal + negkey + DIoU (matched gt is already in LDS) ----
  float fl = focal_one(l, pos ? 1.0f : 0.0f);
  negkey[idx] = pos ? 0u : __float_as_uint(fl);  // fl > 0 strictly; 0 sentinel below all negatives
  float locv = pos ? diou_one(p, sg2[bidx]) : 0.0f;
  if (!pos) {
    uint32_t kb = __float_as_uint(fl);
    atomicAdd(&hc[kb >> SHB], 1u);       // 256 keys into 2048 bins: ~conflict-free
    atomicAdd(&hs[kb >> SHB], fl);
  }

  // lane l holds the wave's column max for gt l; build cross-block comparable u64 key
  uint32_t winlane = 63u - (colkey & 63u);
  uint32_t ganchor = (uint32_t)(bx * 256 + wave * 64) + winlane;
  unsigned long long wkey = ((unsigned long long)(colkey & 0xFFFFFFC0u) << 32)
                          | (unsigned)~ganchor;  // smaller global idx wins ties
  spart[wave][lane] = wkey;

  // per-wave partials
  float flp = pos ? fl : 0.0f;
  float np1 = pos ? 1.0f : 0.0f;
  float lv = locv;
  for (int o = 32; o; o >>= 1) {
    lv  += __shfl_down(lv, o);
    flp += __shfl_down(flp, o);
    np1 += __shfl_down(np1, o);
  }
  if (lane == 0) { sl[wave] = lv; sf[wave] = flp; sn[wave] = np1; }
  __syncthreads();

  // flush nonzero hist bins, gt partial, block partials
  for (int i = t; i < NBIN; i += 256) {
    uint32_t c = hc[i];
    if (c) {
      atomicAdd(&hist_cnt[img * NBIN + i], c);
      atomicAdd(&hist_sum[img * NBIN + i], hs[i]);
    }
  }
  if (t < G_N) {
    unsigned long long m = spart[0][t];
    if (spart[1][t] > m) m = spart[1][t];
    if (spart[2][t] > m) m = spart[2][t];
    if (spart[3][t] > m) m = spart[3][t];
    gt_part[(((size_t)(img << 8) | bx) << 6) | t] = m;  // coalesced 512B store
  }
  if (t == 0) {
    const int pi = img * 256 + bx;
    part_loc[pi] = sl[0] + sl[1] + sl[2] + sl[3];
    part_fl[pi]  = sf[0] + sf[1] + sf[2] + sf[3];
    part_np[pi]  = sn[0] + sn[1] + sn[2] + sn[3];  // integer-valued, exact
  }
}

// ---------------- K2: force+fixup + radix-histogram top-k (no compaction, no single-address atomics) ----------------
__global__ __launch_bounds__(1024) void dl_select(
    uint32_t* negkey,   // no __restrict__: read after in-kernel atomicExch fixup
    const unsigned long long* __restrict__ gt_part,
    const uint32_t* __restrict__ hist_cnt, const float* __restrict__ hist_sum,
    const float* __restrict__ part_loc, const float* __restrict__ part_fl,
    const float* __restrict__ part_np,
    const float4* __restrict__ bbox, const float* __restrict__ conf,
    const float4* __restrict__ gt, const uint8_t* __restrict__ best_idx,
    float* __restrict__ acc, uint32_t* __restrict__ done_ctr, float* __restrict__ out) {
  const int img = blockIdx.x;
  const int t = threadIdx.x;
  uint32_t* negk = negkey + (size_t)img * A_N;
  const uint4* k4 = (const uint4*)negk;
  const int N4 = A_N / 4;  // 16384

  __shared__ uint32_t cnt[NBIN];     // L1: bits[31:21]
  __shared__ float    bsum[NBIN];
  __shared__ uint32_t hc2[NBIN];     // L2: bits[20:10] of boundary-L1-bin keys
  __shared__ float    hs2[NBIN];
  __shared__ uint32_t cnt3[1024];    // L3: bits[9:0] (exact values)
  __shared__ unsigned long long gred[16][G_N];
  __shared__ float s3[3][4];
  __shared__ float redf[16];
  __shared__ float np_sh, psum_sh, loc_sh, sstar_sh, sstar2_sh, negsum_sh;
  __shared__ float fix_l, fix_f, fix_n;
  __shared__ uint32_t bstar_sh, cstar_sh, b2_sh, c2_sh, j3_sh, c3_sh;

  // ---- region A: load L1 hist, zero L2/L3, stage gt_part, reduce block partials ----
  for (int i = t; i < NBIN; i += 1024) {
    cnt[i]  = hist_cnt[img * NBIN + i];
    bsum[i] = hist_sum[img * NBIN + i];
    hc2[i] = 0u; hs2[i] = 0.f;
  }
  cnt3[t] = 0u;
  {
    const int g = t & 63, ch = t >> 6;   // 16 chunks x 64 gts
    unsigned long long m = 0ull;
    #pragma unroll 4
    for (int j = 0; j < 16; ++j) {
      unsigned long long v = gt_part[(((size_t)(img << 8) | (ch * 16 + j)) << 6) | g];
      if (v > m) m = v;
    }
    gred[ch][g] = m;
  }
  float lv = 0.f, fv = 0.f, nv = 0.f;
  if (t < 256) {
    lv = part_loc[img * 256 + t];
    fv = part_fl[img * 256 + t];
    nv = part_np[img * 256 + t];
  }
  for (int o = 32; o; o >>= 1) {
    lv += __shfl_down(lv, o);
    fv += __shfl_down(fv, o);
    nv += __shfl_down(nv, o);
  }
  if (t < 256 && (t & 63) == 0) { s3[0][t >> 6] = lv; s3[1][t >> 6] = fv; s3[2][t >> 6] = nv; }
  __syncthreads();

  // ---- region B (wave 0): per-gt final argmax + forced-positive fixup ----
  if (t < 64) {
    unsigned long long m = gred[0][t];
    #pragma unroll
    for (int c = 1; c < 16; ++c) if (gred[c][t] > m) m = gred[c][t];
    // all-zero column: ratio bits 0 -> max low-word = ~0 -> anchor 0 (numpy argmax)
    uint32_t a = ~(uint32_t)(m & 0xFFFFFFFFull);
    // dedupe multiple gts forcing the same anchor; skips already-positive anchors
    uint32_t old = atomicExch(&negk[a], 0u);
    float dl = 0.f, df = 0.f, dn = 0.f;
    if (old != 0u) {
      dn = 1.f;
      float fln = __uint_as_float(old);
      uint32_t bin = old >> SHB;
      atomicSub(&cnt[bin], 1u);          // remove from negative hist
      atomicAdd(&bsum[bin], -fln);
      const int ai = img * A_N + (int)a;
      df = focal_one(conf[ai], 1.0f);    // now a positive
      dl = diou_one(bbox[ai], gt[img * G_N + best_idx[ai]]);
    }
    for (int o = 32; o; o >>= 1) {
      dl += __shfl_down(dl, o);
      df += __shfl_down(df, o);
      dn += __shfl_down(dn, o);
    }
    if (t == 0) { fix_l = dl; fix_f = df; fix_n = dn; }
  }
  __threadfence();
  __syncthreads();

  if (t == 0) {
    loc_sh  = s3[0][0] + s3[0][1] + s3[0][2] + s3[0][3] + fix_l;
    psum_sh = s3[1][0] + s3[1][1] + s3[1][2] + s3[1][3] + fix_f;
    np_sh   = s3[2][0] + s3[2][1] + s3[2][2] + s3[2][3] + fix_n;
    negsum_sh = 0.f;
  }
  __syncthreads();

  const int np = (int)(np_sh + 0.5f);
  const int k = min(A_N - np, 3 * np);

  if (k > 0) {
    // ---- L1 scan (wave 0): threshold bin b*: C(>b*) < k <= C(>=b*) ----
    if (t < 64) {
      const int CH = NBIN / 64;
      const int lob = NBIN - CH * (t + 1);   // lane 0 owns the TOP chunk
      uint32_t csum = 0;
      for (int b = lob; b < lob + CH; ++b) csum += cnt[b];
      uint32_t pre = csum;
      for (int o = 1; o < 64; o <<= 1) { uint32_t u = __shfl_up(pre, o); if (t >= o) pre += u; }
      uint32_t run = pre - csum;
      for (int b = lob + CH - 1; b >= lob; --b) {
        uint32_t c = cnt[b];
        if (run < (uint32_t)k && run + c >= (uint32_t)k) { bstar_sh = (uint32_t)b; cstar_sh = run; }
        run += c;
      }
    }
    __syncthreads();
    const uint32_t bstar = bstar_sh;
    const uint32_t cbin = cnt[bstar];
    const uint32_t r = (uint32_t)k - cstar_sh;  // 1 <= r <= cbin

    // ---- Sstar = sum of keys in L1 bins > b* (all threads) ----
    float s = 0.f;
    for (int i = t; i < NBIN; i += 1024) if (i > (int)bstar) s += bsum[i];
    for (int o = 32; o; o >>= 1) s += __shfl_down(s, o);
    if ((t & 63) == 0) redf[t >> 6] = s;
    __syncthreads();
    if (t == 0) {
      float ss = 0.f;
      #pragma unroll
      for (int w = 0; w < 16; ++w) ss += redf[w];
      sstar_sh = ss;
    }
    __syncthreads();

    if (r == cbin) {
      if (t == 0) negsum_sh = sstar_sh + bsum[bstar];
    } else {
      // ---- streaming pass 1: L2 hist of boundary-bin keys (atomics spread over 2048 bins) ----
      for (int i = t; i < N4; i += 1024) {
        uint4 v = k4[i];
        if (v.x != 0u && (v.x >> SHB) == bstar) { atomicAdd(&hc2[(v.x >> 10) & 2047u], 1u); atomicAdd(&hs2[(v.x >> 10) & 2047u], __uint_as_float(v.x)); }
        if (v.y != 0u && (v.y >> SHB) == bstar) { atomicAdd(&hc2[(v.y >> 10) & 2047u], 1u); atomicAdd(&hs2[(v.y >> 10) & 2047u], __uint_as_float(v.y)); }
        if (v.z != 0u && (v.z >> SHB) == bstar) { atomicAdd(&hc2[(v.z >> 10) & 2047u], 1u); atomicAdd(&hs2[(v.z >> 10) & 2047u], __uint_as_float(v.z)); }
        if (v.w != 0u && (v.w >> SHB) == bstar) { atomicAdd(&hc2[(v.w >> 10) & 2047u], 1u); atomicAdd(&hs2[(v.w >> 10) & 2047u], __uint_as_float(v.w)); }
      }
      __syncthreads();

      // ---- L2 scan (wave 0): sub-bin b2*: C2(>b2*) < r <= C2(>=b2*) ----
      if (t < 64) {
        const int CH = NBIN / 64;
        const int lob = NBIN - CH * (t + 1);
        uint32_t csum = 0;
        for (int b = lob; b < lob + CH; ++b) csum += hc2[b];
        uint32_t pre = csum;
        for (int o = 1; o < 64; o <<= 1) { uint32_t u = __shfl_up(pre, o); if (t >= o) pre += u; }
        uint32_t run = pre - csum;
        for (int b = lob + CH - 1; b >= lob; --b) {
          uint32_t c = hc2[b];
          if (run < r && run + c >= r) { b2_sh = (uint32_t)b; c2_sh = run; }
          run += c;
        }
      }
      __syncthreads();
      const uint32_t b2 = b2_sh;
      const uint32_t cbin2 = hc2[b2];
      const uint32_t r3 = r - c2_sh;  // 1 <= r3 <= cbin2

      // ---- Sstar2 = sum of keys in L2 bins > b2* (all threads) ----
      float s2 = 0.f;
      for (int i = t; i < NBIN; i += 1024) if (i > (int)b2) s2 += hs2[i];
      for (int o = 32; o; o >>= 1) s2 += __shfl_down(s2, o);
      if ((t & 63) == 0) redf[t >> 6] = s2;
      __syncthreads();
      if (t == 0) {
        float ss = 0.f;
        #pragma unroll
        for (int w = 0; w < 16; ++w) ss += redf[w];
        sstar2_sh = ss;
      }
      __syncthreads();

      if (r3 == cbin2) {
        if (t == 0) negsum_sh = sstar_sh + sstar2_sh + hs2[b2];
      } else {
        // ---- streaming pass 2: L3 exact-value hist (top-22-bit filter; ~cbin2 spread atomics) ----
        const uint32_t top22 = (bstar << 11) | b2;
        for (int i = t; i < N4; i += 1024) {
          uint4 v = k4[i];
          if (v.x != 0u && (v.x >> 10) == top22) atomicAdd(&cnt3[v.x & 1023u], 1u);
          if (v.y != 0u && (v.y >> 10) == top22) atomicAdd(&cnt3[v.y & 1023u], 1u);
          if (v.z != 0u && (v.z >> 10) == top22) atomicAdd(&cnt3[v.z & 1023u], 1u);
          if (v.w != 0u && (v.w >> 10) == top22) atomicAdd(&cnt3[v.w & 1023u], 1u);
        }
        __syncthreads();

        // ---- L3 scan (wave 0): exact value j*: C3(>j*) < r3 <= C3(>=j*) ----
        if (t < 64) {
          const int CH = 1024 / 64;  // 16
          const int lob = 1024 - CH * (t + 1);
          uint32_t csum = 0;
          for (int b = lob; b < lob + CH; ++b) csum += cnt3[b];
          uint32_t pre = csum;
          for (int o = 1; o < 64; o <<= 1) { uint32_t u = __shfl_up(pre, o); if (t >= o) pre += u; }
          uint32_t run = pre - csum;
          for (int b = lob + CH - 1; b >= lob; --b) {
            uint32_t c = cnt3[b];
            if (run < r3 && run + c >= r3) { j3_sh = (uint32_t)b; c3_sh = run; }
            run += c;
          }
        }
        __syncthreads();
        const uint32_t j3 = j3_sh;
        const uint32_t hibits = (bstar << SHB) | (b2 << 10);

        // ---- exact tail sum: bins above j* + boundary copies of val(j*) ----
        float s3v = 0.f;
        if (t > (int)j3 && cnt3[t]) {
          s3v = (float)cnt3[t] * __uint_as_float(hibits | (uint32_t)t);
        }
        for (int o = 32; o; o >>= 1) s3v += __shfl_down(s3v, o);
        if ((t & 63) == 0) redf[t >> 6] = s3v;
        __syncthreads();
        if (t == 0) {
          float ss = 0.f;
          #pragma unroll
          for (int w = 0; w < 16; ++w) ss += redf[w];
          negsum_sh = sstar_sh + sstar2_sh + ss
                    + (float)(int)(r3 - c3_sh) * __uint_as_float(hibits | j3);
        }
      }
    }
  }
  __syncthreads();
  if (t == 0) {
    acc[img] = loc_sh;
    acc[32 + img] = (float)np;
    acc[48 + img] = (psum_sh + negsum_sh) / fmaxf((float)(np + k), 1.0f);
    // ---- last-block finale: fence + device-scope counter ----
    __threadfence();
    uint32_t old = atomicAdd(done_ctr, 1u);
    if (old == (uint32_t)(B_N - 1)) {
      __threadfence();
      float sl = 0.f, sc = 0.f, sn = 0.f;
      for (int i = 0; i < B_N; ++i) {
        sl += acc[i];
        sc += acc[48 + i];
        sn += acc[32 + i];
      }
      float tp = fmaxf(sn, 1.0f);
      float al = sl / tp;
      float ac = sc / tp;
      out[0] = al + ac;
      out[1] = ac;
      out[2] = al;
    }
  }
}

extern "C" void kernel_launch(void* const* d_in, const int* in_sizes, int n_in,
                              void* d_out, int out_size, void* d_ws, size_t ws_size,
                              hipStream_t stream) {
  (void)in_sizes; (void)n_in; (void)out_size; (void)ws_size;

  const float4* bbox = (const float4*)d_in[0];   // [B, A, 4] f32
  const float*  conf = (const float*)d_in[1];    // [B, A] f32
  const float4* gt   = (const float4*)d_in[2];   // [B, G, 4] f32
  float* out = (float*)d_out;

  char* ws = (char*)d_ws;
  uint32_t*           negkey   = (uint32_t*)(ws);                       // 4 MiB
  unsigned long long* gt_part  = (unsigned long long*)(ws + (4u << 20));// 2 MiB [16][256][64]
  uint8_t*            best_idx = (uint8_t*)(ws + (6u << 20));          // 1 MiB
  char* hb = ws + (7u << 20);
  uint32_t* hist_cnt = (uint32_t*)(hb);                                // 128 KiB [16][2048]
  float*    hist_sum = (float*)(hb + (size_t)B_N * NBIN * 4);          // 128 KiB (contiguous)
  char* tail = hb + 2 * (size_t)B_N * NBIN * 4;
  float* part_loc = (float*)(tail);                                    // 16 KiB
  float* part_fl  = (float*)(tail + 16384);
  float* part_np  = (float*)(tail + 32768);
  float* acc      = (float*)(tail + 49152);                            // 64 floats
  uint32_t* done_ctr = (uint32_t*)(tail + 49152 + 256);

  dl_init<<<64, 1024, 0, stream>>>(hist_cnt /* zeroes cnt+sum (contiguous) */, done_ctr);
  dl_pass1<<<dim3(A_N / 256, B_N), 256, 0, stream>>>(bbox, conf, gt, best_idx, negkey,
                                                     gt_part, hist_cnt, hist_sum,
                                                     part_loc, part_fl, part_np);
  dl_select<<<B_N, 1024, 0, stream>>>(negkey, gt_part, hist_cnt, hist_sum,
                                      part_loc, part_fl, part_np,
                                      bbox, conf, gt, best_idx, acc, done_ctr, out);
}

// Round 11
// 148.234 us; speedup vs baseline: 1.2734x; 1.0166x over previous
//
#include <hip/hip_runtime.h>
#include <stdint.h>

#define A_N 65536
#define B_N 16
#define G_N 64
#define FEPS 1e-7f

#define NBIN 2048
#define SHB  21      // L1 bin = keybits >> 21 (sign + 8 exp + 2 mantissa bits)

// fast focal loss (tolerance path): 2 transcendentals + rcp, ~1e-6 rel err
__device__ __forceinline__ float focal_one(float l, float tt) {
  float e  = __expf(-fabsf(l));                    // e^{-|l|}
  float sp = __logf(1.0f + e);                     // log1p(e^{-|l|})
  bool  tp = tt > 0.5f;
  float ce = (tp ? fmaxf(-l, 0.0f) : fmaxf(l, 0.0f)) + sp;   // BCE-with-logits
  float inv = __builtin_amdgcn_rcpf(1.0f + e);     // 1/(1+e)
  float sig = (l >= 0.0f) ? inv : e * inv;         // sigmoid(l)
  float om  = tp ? (1.0f - sig) : sig;             // 1 - p_t
  om = fminf(fmaxf(om, FEPS), 1.0f - FEPS);
  float alpha = tp ? 0.25f : 0.75f;
  return alpha * om * om * ce;
}

// DIoU loss for one (pred, gt) pair (tolerance path)
__device__ __forceinline__ float diou_one(float4 p, float4 q) {
  float ap = (p.z - p.x) * (p.w - p.y);
  float ag = (q.z - q.x) * (q.w - q.y);
  float ix1 = fmaxf(p.x, q.x), iy1 = fmaxf(p.y, q.y);
  float ix2 = fminf(p.z, q.z), iy2 = fminf(p.w, q.w);
  float iw = fmaxf(ix2 - ix1, 0.0f), ih = fmaxf(iy2 - iy1, 0.0f);
  float inter = iw * ih;
  float iou = inter / (ap + ag - inter + FEPS);
  float cpx = (p.x + p.z) * 0.5f, cpy = (p.y + p.w) * 0.5f;
  float cgx = (q.x + q.z) * 0.5f, cgy = (q.y + q.w) * 0.5f;
  float dx = cpx - cgx, dy = cpy - cgy;
  float cd2 = dx * dx + dy * dy;
  float ex1 = fminf(p.x, q.x), ey1 = fminf(p.y, q.y);
  float ex2 = fmaxf(p.z, q.z), ey2 = fmaxf(p.w, q.w);
  float ddx = ex2 - ex1, ddy = ey2 - ey1;
  float dg2 = ddx * ddx + ddy * ddy + FEPS;
  return 1.0f - iou + cd2 / dg2;   // LOC_LOSS_WEIGHT = 1
}

// ---------------- K0: zero global hist (cnt+sum contiguous, 65536 words) ----------------
__global__ void dl_init(uint32_t* __restrict__ histz) {
  int i = blockIdx.x * 1024 + threadIdx.x;
  histz[i] = 0u;
}

// ---------------- K1: matching (packed-key row argmax + rotating column argmax) FUSED with
// focal/negkey/DIoU/hist/partials — one pass over all anchors (identical to round 9) ----------------
__global__ __launch_bounds__(256) void dl_pass1(
    const float4* __restrict__ bbox, const float* __restrict__ conf,
    const float4* __restrict__ gt,
    uint8_t* __restrict__ best_idx, uint32_t* __restrict__ negkey,
    unsigned long long* __restrict__ gt_part,
    uint32_t* __restrict__ hist_cnt, float* __restrict__ hist_sum,
    float* __restrict__ part_loc, float* __restrict__ part_fl, float* __restrict__ part_np) {
  const int img = blockIdx.y;
  const int bx  = blockIdx.x;
  const int t   = threadIdx.x;
  const int wave = t >> 6, lane = t & 63;
  const int a = bx * 256 + t;
  const int idx = img * A_N + a;

  __shared__ float4 sg2[2 * G_N];   // gt boxes doubled: index lane+j needs no &63 wrap
  __shared__ float  sga2[2 * G_N];
  __shared__ unsigned long long spart[4][G_N];
  __shared__ uint32_t hc[NBIN];
  __shared__ float    hs[NBIN];
  __shared__ float sl[4], sf[4], sn[4];

  for (int i = t; i < NBIN; i += 256) { hc[i] = 0u; hs[i] = 0.f; }
  if (t < G_N) {
    float4 q0 = gt[img * G_N + t];
    // exact f32, no contraction (matches numpy bit-for-bit)
    float qa0 = __fmul_rn(__fsub_rn(q0.z, q0.x), __fsub_rn(q0.w, q0.y));
    sg2[t] = q0;  sg2[t + G_N] = q0;
    sga2[t] = qa0; sga2[t + G_N] = qa0;
  }
  __syncthreads();

  float4 p = bbox[idx];
  float pa = __fmul_rn(__fsub_rn(p.z, p.x), __fsub_rn(p.w, p.y));
  float l = conf[idx];

  float posm = -1.f;
  uint32_t rowkey = 0u;                       // packed (ratio_bits | 63-g) row max
  uint32_t colkey = 0u;                       // rotating column-max register
  uint32_t tb = 63u - (uint32_t)lane;         // rotating row tie-break = 63-g, g=(lane+j)&63
  const int rotsrc = (lane + 1) & 63;         // pull from next lane after each iter
  const uint32_t lanecomp = 63u - (uint32_t)lane;  // column tie-break (smaller lane wins)

  #pragma unroll 8
  for (int j = 0; j < G_N; ++j) {
    float4 q = sg2[lane + j];                 // fixed addr reg + offset:j*16
    float qa = sga2[lane + j];
    float ix1 = fmaxf(p.x, q.x), iy1 = fmaxf(p.y, q.y);
    float ix2 = fminf(p.z, q.z), iy2 = fminf(p.w, q.w);
    float iw = fmaxf(__fsub_rn(ix2, ix1), 0.f);
    float ih = fmaxf(__fsub_rn(iy2, iy1), 0.f);
    float inter = __fmul_rn(iw, ih);
    float den = __fadd_rn(__fsub_rn(__fadd_rn(pa, qa), inter), FEPS);  // exact numpy den
    // pos threshold EXACT: iou > 0.5 <=> sign(2*inter - den) > 0 (RN preserves sign)
    posm = fmaxf(posm, __fmaf_rn(2.f, inter, -den));
    // shared approx ratio (1-ulp rcp); near-tie flips are measure-zero on random data
    float ratio = inter * __builtin_amdgcn_rcpf(den);
    uint32_t base = __float_as_uint(ratio) & 0xFFFFFFC0u;
    uint32_t rkey = base | tb;                // smaller g wins ties (first occurrence)
    if (rkey > rowkey) rowkey = rkey;
    uint32_t ckey = base | lanecomp;
    if (ckey > colkey) colkey = ckey;
    colkey = __shfl(colkey, rotsrc);          // register now belongs to g+1
    tb = (tb - 1u) & 63u;                     // g+1 -> tie-break decrements (wraps 0->63)
  }

  const bool pos = posm > 0.f;
  const int bidx = 63 - (int)(rowkey & 63u);
  best_idx[idx] = (uint8_t)bidx;

  // ---- fused focal + negkey + DIoU (matched gt is already in LDS) ----
  float fl = focal_one(l, pos ? 1.0f : 0.0f);
  negkey[idx] = pos ? 0u : __float_as_uint(fl);  // fl > 0 strictly; 0 sentinel below all negatives
  float locv = pos ? diou_one(p, sg2[bidx]) : 0.0f;
  if (!pos) {
    uint32_t kb = __float_as_uint(fl);
    atomicAdd(&hc[kb >> SHB], 1u);       // 256 keys into 2048 bins: ~conflict-free
    atomicAdd(&hs[kb >> SHB], fl);
  }

  // lane l holds the wave's column max for gt l; build cross-block comparable u64 key
  uint32_t winlane = 63u - (colkey & 63u);
  uint32_t ganchor = (uint32_t)(bx * 256 + wave * 64) + winlane;
  unsigned long long wkey = ((unsigned long long)(colkey & 0xFFFFFFC0u) << 32)
                          | (unsigned)~ganchor;  // smaller global idx wins ties
  spart[wave][lane] = wkey;

  // per-wave partials
  float flp = pos ? fl : 0.0f;
  float np1 = pos ? 1.0f : 0.0f;
  float lv = locv;
  for (int o = 32; o; o >>= 1) {
    lv  += __shfl_down(lv, o);
    flp += __shfl_down(flp, o);
    np1 += __shfl_down(np1, o);
  }
  if (lane == 0) { sl[wave] = lv; sf[wave] = flp; sn[wave] = np1; }
  __syncthreads();

  // flush nonzero hist bins, gt partial, block partials
  for (int i = t; i < NBIN; i += 256) {
    uint32_t c = hc[i];
    if (c) {
      atomicAdd(&hist_cnt[img * NBIN + i], c);
      atomicAdd(&hist_sum[img * NBIN + i], hs[i]);
    }
  }
  if (t < G_N) {
    unsigned long long m = spart[0][t];
    if (spart[1][t] > m) m = spart[1][t];
    if (spart[2][t] > m) m = spart[2][t];
    if (spart[3][t] > m) m = spart[3][t];
    gt_part[(((size_t)(img << 8) | bx) << 6) | t] = m;  // coalesced 512B store
  }
  if (t == 0) {
    const int pi = img * 256 + bx;
    part_loc[pi] = sl[0] + sl[1] + sl[2] + sl[3];
    part_fl[pi]  = sf[0] + sf[1] + sf[2] + sf[3];
    part_np[pi]  = sn[0] + sn[1] + sn[2] + sn[3];  // integer-valued, exact
  }
}

// ---------------- K2: force+fixup + radix-histogram top-k — NO fences, no finale ----------------
__global__ __launch_bounds__(1024) void dl_select(
    uint32_t* negkey,   // no __restrict__: read after in-kernel atomicExch fixup
    const unsigned long long* __restrict__ gt_part,
    const uint32_t* __restrict__ hist_cnt, const float* __restrict__ hist_sum,
    const float* __restrict__ part_loc, const float* __restrict__ part_fl,
    const float* __restrict__ part_np,
    const float4* __restrict__ bbox, const float* __restrict__ conf,
    const float4* __restrict__ gt, const uint8_t* __restrict__ best_idx,
    float* __restrict__ acc) {
  const int img = blockIdx.x;
  const int t = threadIdx.x;
  uint32_t* negk = negkey + (size_t)img * A_N;
  const uint4* k4 = (const uint4*)negk;
  const int N4 = A_N / 4;  // 16384

  __shared__ uint32_t cnt[NBIN];     // L1: bits[31:21]
  __shared__ float    bsum[NBIN];
  __shared__ uint32_t hc2[NBIN];     // L2: bits[20:10] of boundary-L1-bin keys
  __shared__ float    hs2[NBIN];
  __shared__ uint32_t cnt3[1024];    // L3: bits[9:0] (exact values)
  __shared__ unsigned long long gred[16][G_N];
  __shared__ float s3[3][4];
  __shared__ float redf[16];
  __shared__ float np_sh, psum_sh, loc_sh, sstar_sh, sstar2_sh, negsum_sh;
  __shared__ float fix_l, fix_f, fix_n;
  __shared__ uint32_t bstar_sh, cstar_sh, b2_sh, c2_sh, j3_sh, c3_sh;

  // ---- region A: load L1 hist, zero L2/L3, stage gt_part, reduce block partials ----
  for (int i = t; i < NBIN; i += 1024) {
    cnt[i]  = hist_cnt[img * NBIN + i];
    bsum[i] = hist_sum[img * NBIN + i];
    hc2[i] = 0u; hs2[i] = 0.f;
  }
  cnt3[t] = 0u;
  {
    const int g = t & 63, ch = t >> 6;   // 16 chunks x 64 gts
    unsigned long long m = 0ull;
    #pragma unroll 4
    for (int j = 0; j < 16; ++j) {
      unsigned long long v = gt_part[(((size_t)(img << 8) | (ch * 16 + j)) << 6) | g];
      if (v > m) m = v;
    }
    gred[ch][g] = m;
  }
  float lv = 0.f, fv = 0.f, nv = 0.f;
  if (t < 256) {
    lv = part_loc[img * 256 + t];
    fv = part_fl[img * 256 + t];
    nv = part_np[img * 256 + t];
  }
  for (int o = 32; o; o >>= 1) {
    lv += __shfl_down(lv, o);
    fv += __shfl_down(fv, o);
    nv += __shfl_down(nv, o);
  }
  if (t < 256 && (t & 63) == 0) { s3[0][t >> 6] = lv; s3[1][t >> 6] = fv; s3[2][t >> 6] = nv; }
  __syncthreads();

  // ---- region B (wave 0): per-gt final argmax + forced-positive fixup ----
  // No __threadfence needed: the atomicExch'd negkey lines are consumed only below
  // this block's __syncthreads (same-block visibility via cache-coherent atomics).
  if (t < 64) {
    unsigned long long m = gred[0][t];
    #pragma unroll
    for (int c = 1; c < 16; ++c) if (gred[c][t] > m) m = gred[c][t];
    // all-zero column: ratio bits 0 -> max low-word = ~0 -> anchor 0 (numpy argmax)
    uint32_t a = ~(uint32_t)(m & 0xFFFFFFFFull);
    // dedupe multiple gts forcing the same anchor; skips already-positive anchors
    uint32_t old = atomicExch(&negk[a], 0u);
    float dl = 0.f, df = 0.f, dn = 0.f;
    if (old != 0u) {
      dn = 1.f;
      float fln = __uint_as_float(old);
      uint32_t bin = old >> SHB;
      atomicSub(&cnt[bin], 1u);          // remove from negative hist
      atomicAdd(&bsum[bin], -fln);
      const int ai = img * A_N + (int)a;
      df = focal_one(conf[ai], 1.0f);    // now a positive
      dl = diou_one(bbox[ai], gt[img * G_N + best_idx[ai]]);
    }
    for (int o = 32; o; o >>= 1) {
      dl += __shfl_down(dl, o);
      df += __shfl_down(df, o);
      dn += __shfl_down(dn, o);
    }
    if (t == 0) { fix_l = dl; fix_f = df; fix_n = dn; }
  }
  __syncthreads();

  if (t == 0) {
    loc_sh  = s3[0][0] + s3[0][1] + s3[0][2] + s3[0][3] + fix_l;
    psum_sh = s3[1][0] + s3[1][1] + s3[1][2] + s3[1][3] + fix_f;
    np_sh   = s3[2][0] + s3[2][1] + s3[2][2] + s3[2][3] + fix_n;
    negsum_sh = 0.f;
  }
  __syncthreads();

  const int np = (int)(np_sh + 0.5f);
  const int k = min(A_N - np, 3 * np);

  if (k > 0) {
    // ---- L1 scan (wave 0): threshold bin b*: C(>b*) < k <= C(>=b*) ----
    if (t < 64) {
      const int CH = NBIN / 64;
      const int lob = NBIN - CH * (t + 1);   // lane 0 owns the TOP chunk
      uint32_t csum = 0;
      for (int b = lob; b < lob + CH; ++b) csum += cnt[b];
      uint32_t pre = csum;
      for (int o = 1; o < 64; o <<= 1) { uint32_t u = __shfl_up(pre, o); if (t >= o) pre += u; }
      uint32_t run = pre - csum;
      for (int b = lob + CH - 1; b >= lob; --b) {
        uint32_t c = cnt[b];
        if (run < (uint32_t)k && run + c >= (uint32_t)k) { bstar_sh = (uint32_t)b; cstar_sh = run; }
        run += c;
      }
    }
    __syncthreads();
    const uint32_t bstar = bstar_sh;
    const uint32_t cbin = cnt[bstar];
    const uint32_t r = (uint32_t)k - cstar_sh;  // 1 <= r <= cbin

    // ---- Sstar = sum of keys in L1 bins > b* (all threads) ----
    float s = 0.f;
    for (int i = t; i < NBIN; i += 1024) if (i > (int)bstar) s += bsum[i];
    for (int o = 32; o; o >>= 1) s += __shfl_down(s, o);
    if ((t & 63) == 0) redf[t >> 6] = s;
    __syncthreads();
    if (t == 0) {
      float ss = 0.f;
      #pragma unroll
      for (int w = 0; w < 16; ++w) ss += redf[w];
      sstar_sh = ss;
    }
    __syncthreads();

    if (r == cbin) {
      if (t == 0) negsum_sh = sstar_sh + bsum[bstar];
    } else {
      // ---- streaming pass 1: L2 hist of boundary-bin keys (atomics spread over 2048 bins) ----
      for (int i = t; i < N4; i += 1024) {
        uint4 v = k4[i];
        if (v.x != 0u && (v.x >> SHB) == bstar) { atomicAdd(&hc2[(v.x >> 10) & 2047u], 1u); atomicAdd(&hs2[(v.x >> 10) & 2047u], __uint_as_float(v.x)); }
        if (v.y != 0u && (v.y >> SHB) == bstar) { atomicAdd(&hc2[(v.y >> 10) & 2047u], 1u); atomicAdd(&hs2[(v.y >> 10) & 2047u], __uint_as_float(v.y)); }
        if (v.z != 0u && (v.z >> SHB) == bstar) { atomicAdd(&hc2[(v.z >> 10) & 2047u], 1u); atomicAdd(&hs2[(v.z >> 10) & 2047u], __uint_as_float(v.z)); }
        if (v.w != 0u && (v.w >> SHB) == bstar) { atomicAdd(&hc2[(v.w >> 10) & 2047u], 1u); atomicAdd(&hs2[(v.w >> 10) & 2047u], __uint_as_float(v.w)); }
      }
      __syncthreads();

      // ---- L2 scan (wave 0): sub-bin b2*: C2(>b2*) < r <= C2(>=b2*) ----
      if (t < 64) {
        const int CH = NBIN / 64;
        const int lob = NBIN - CH * (t + 1);
        uint32_t csum = 0;
        for (int b = lob; b < lob + CH; ++b) csum += hc2[b];
        uint32_t pre = csum;
        for (int o = 1; o < 64; o <<= 1) { uint32_t u = __shfl_up(pre, o); if (t >= o) pre += u; }
        uint32_t run = pre - csum;
        for (int b = lob + CH - 1; b >= lob; --b) {
          uint32_t c = hc2[b];
          if (run < r && run + c >= r) { b2_sh = (uint32_t)b; c2_sh = run; }
          run += c;
        }
      }
      __syncthreads();
      const uint32_t b2 = b2_sh;
      const uint32_t cbin2 = hc2[b2];
      const uint32_t r3 = r - c2_sh;  // 1 <= r3 <= cbin2

      // ---- Sstar2 = sum of keys in L2 bins > b2* (all threads) ----
      float s2 = 0.f;
      for (int i = t; i < NBIN; i += 1024) if (i > (int)b2) s2 += hs2[i];
      for (int o = 32; o; o >>= 1) s2 += __shfl_down(s2, o);
      if ((t & 63) == 0) redf[t >> 6] = s2;
      __syncthreads();
      if (t == 0) {
        float ss = 0.f;
        #pragma unroll
        for (int w = 0; w < 16; ++w) ss += redf[w];
        sstar2_sh = ss;
      }
      __syncthreads();

      if (r3 == cbin2) {
        if (t == 0) negsum_sh = sstar_sh + sstar2_sh + hs2[b2];
      } else {
        // ---- streaming pass 2: L3 exact-value hist (top-22-bit filter; spread atomics) ----
        const uint32_t top22 = (bstar << 11) | b2;
        for (int i = t; i < N4; i += 1024) {
          uint4 v = k4[i];
          if (v.x != 0u && (v.x >> 10) == top22) atomicAdd(&cnt3[v.x & 1023u], 1u);
          if (v.y != 0u && (v.y >> 10) == top22) atomicAdd(&cnt3[v.y & 1023u], 1u);
          if (v.z != 0u && (v.z >> 10) == top22) atomicAdd(&cnt3[v.z & 1023u], 1u);
          if (v.w != 0u && (v.w >> 10) == top22) atomicAdd(&cnt3[v.w & 1023u], 1u);
        }
        __syncthreads();

        // ---- L3 scan (wave 0): exact value j*: C3(>j*) < r3 <= C3(>=j*) ----
        if (t < 64) {
          const int CH = 1024 / 64;  // 16
          const int lob = 1024 - CH * (t + 1);
          uint32_t csum = 0;
          for (int b = lob; b < lob + CH; ++b) csum += cnt3[b];
          uint32_t pre = csum;
          for (int o = 1; o < 64; o <<= 1) { uint32_t u = __shfl_up(pre, o); if (t >= o) pre += u; }
          uint32_t run = pre - csum;
          for (int b = lob + CH - 1; b >= lob; --b) {
            uint32_t c = cnt3[b];
            if (run < r3 && run + c >= r3) { j3_sh = (uint32_t)b; c3_sh = run; }
            run += c;
          }
        }
        __syncthreads();
        const uint32_t j3 = j3_sh;
        const uint32_t hibits = (bstar << SHB) | (b2 << 10);

        // ---- exact tail sum: bins above j* + boundary copies of val(j*) ----
        float s3v = 0.f;
        if (t > (int)j3 && cnt3[t]) {
          s3v = (float)cnt3[t] * __uint_as_float(hibits | (uint32_t)t);
        }
        for (int o = 32; o; o >>= 1) s3v += __shfl_down(s3v, o);
        if ((t & 63) == 0) redf[t >> 6] = s3v;
        __syncthreads();
        if (t == 0) {
          float ss = 0.f;
          #pragma unroll
          for (int w = 0; w < 16; ++w) ss += redf[w];
          negsum_sh = sstar_sh + sstar2_sh + ss
                    + (float)(int)(r3 - c3_sh) * __uint_as_float(hibits | j3);
        }
      }
    }
  }
  __syncthreads();
  if (t == 0) {
    acc[img] = loc_sh;
    acc[32 + img] = (float)np;
    acc[48 + img] = (psum_sh + negsum_sh) / fmaxf((float)(np + k), 1.0f);
  }
}

// ---------------- K3: final combine (kernel boundary = free device-wide release) ----------------
__global__ void dl_final(const float* __restrict__ acc, float* __restrict__ out) {
  if (threadIdx.x == 0 && blockIdx.x == 0) {
    float sl = 0.0f, sc = 0.0f, sn = 0.0f;
    for (int i = 0; i < B_N; ++i) {
      sl += acc[i];
      sc += acc[48 + i];
      sn += acc[32 + i];
    }
    float tp = fmaxf(sn, 1.0f);
    float al = sl / tp;
    float ac = sc / tp;
    out[0] = al + ac;
    out[1] = ac;
    out[2] = al;
  }
}

extern "C" void kernel_launch(void* const* d_in, const int* in_sizes, int n_in,
                              void* d_out, int out_size, void* d_ws, size_t ws_size,
                              hipStream_t stream) {
  (void)in_sizes; (void)n_in; (void)out_size; (void)ws_size;

  const float4* bbox = (const float4*)d_in[0];   // [B, A, 4] f32
  const float*  conf = (const float*)d_in[1];    // [B, A] f32
  const float4* gt   = (const float4*)d_in[2];   // [B, G, 4] f32
  float* out = (float*)d_out;

  char* ws = (char*)d_ws;
  uint32_t*           negkey   = (uint32_t*)(ws);                       // 4 MiB
  unsigned long long* gt_part  = (unsigned long long*)(ws + (4u << 20));// 2 MiB [16][256][64]
  uint8_t*            best_idx = (uint8_t*)(ws + (6u << 20));          // 1 MiB
  char* hb = ws + (7u << 20);
  uint32_t* hist_cnt = (uint32_t*)(hb);                                // 128 KiB [16][2048]
  float*    hist_sum = (float*)(hb + (size_t)B_N * NBIN * 4);          // 128 KiB (contiguous)
  char* tail = hb + 2 * (size_t)B_N * NBIN * 4;
  float* part_loc = (float*)(tail);                                    // 16 KiB
  float* part_fl  = (float*)(tail + 16384);
  float* part_np  = (float*)(tail + 32768);
  float* acc      = (float*)(tail + 49152);                            // 64 floats

  dl_init<<<64, 1024, 0, stream>>>(hist_cnt /* zeroes cnt+sum (contiguous) */);
  dl_pass1<<<dim3(A_N / 256, B_N), 256, 0, stream>>>(bbox, conf, gt, best_idx, negkey,
                                                     gt_part, hist_cnt, hist_sum,
                                                     part_loc, part_fl, part_np);
  dl_select<<<B_N, 1024, 0, stream>>>(negkey, gt_part, hist_cnt, hist_sum,
                                      part_loc, part_fl, part_np,
                                      bbox, conf, gt, best_idx, acc);
  dl_final<<<1, 64, 0, stream>>>(acc, out);
}

// Round 12
// 147.452 us; speedup vs baseline: 1.2801x; 1.0053x over previous
//
#include <hip/hip_runtime.h>
#include <stdint.h>

#define A_N 65536
#define B_N 16
#define G_N 64
#define FEPS 1e-7f

#define NBIN 2048
#define SHB  21      // L1 bin = keybits >> 21 (sign + 8 exp + 2 mantissa bits)
#define NB2  8192    // L2 bins = bits[20:8] within the L1 boundary bin
#define NB3  256     // L3 = bits[7:0] exact values

// fast focal loss (tolerance path): 2 transcendentals + rcp, ~1e-6 rel err
__device__ __forceinline__ float focal_one(float l, float tt) {
  float e  = __expf(-fabsf(l));                    // e^{-|l|}
  float sp = __logf(1.0f + e);                     // log1p(e^{-|l|})
  bool  tp = tt > 0.5f;
  float ce = (tp ? fmaxf(-l, 0.0f) : fmaxf(l, 0.0f)) + sp;   // BCE-with-logits
  float inv = __builtin_amdgcn_rcpf(1.0f + e);     // 1/(1+e)
  float sig = (l >= 0.0f) ? inv : e * inv;         // sigmoid(l)
  float om  = tp ? (1.0f - sig) : sig;             // 1 - p_t
  om = fminf(fmaxf(om, FEPS), 1.0f - FEPS);
  float alpha = tp ? 0.25f : 0.75f;
  return alpha * om * om * ce;
}

// DIoU loss for one (pred, gt) pair (tolerance path)
__device__ __forceinline__ float diou_one(float4 p, float4 q) {
  float ap = (p.z - p.x) * (p.w - p.y);
  float ag = (q.z - q.x) * (q.w - q.y);
  float ix1 = fmaxf(p.x, q.x), iy1 = fmaxf(p.y, q.y);
  float ix2 = fminf(p.z, q.z), iy2 = fminf(p.w, q.w);
  float iw = fmaxf(ix2 - ix1, 0.0f), ih = fmaxf(iy2 - iy1, 0.0f);
  float inter = iw * ih;
  float iou = inter / (ap + ag - inter + FEPS);
  float cpx = (p.x + p.z) * 0.5f, cpy = (p.y + p.w) * 0.5f;
  float cgx = (q.x + q.z) * 0.5f, cgy = (q.y + q.w) * 0.5f;
  float dx = cpx - cgx, dy = cpy - cgy;
  float cd2 = dx * dx + dy * dy;
  float ex1 = fminf(p.x, q.x), ey1 = fminf(p.y, q.y);
  float ex2 = fmaxf(p.z, q.z), ey2 = fmaxf(p.w, q.w);
  float ddx = ex2 - ex1, ddy = ey2 - ey1;
  float dg2 = ddx * ddx + ddy * ddy + FEPS;
  return 1.0f - iou + cd2 / dg2;   // LOC_LOSS_WEIGHT = 1
}

// ---------------- K0: zero global hist (cnt+sum contiguous, 65536 words) ----------------
__global__ void dl_init(uint32_t* __restrict__ histz) {
  int i = blockIdx.x * 1024 + threadIdx.x;
  histz[i] = 0u;
}

// ---------------- K1: matching fused with focal/negkey/DIoU/hist/partials.
// LDS diet: qa recomputed in VALU (bit-identical), so inner loop = 2 LDS ops
// (ds_read_b128 gt + ds_bpermute rotation) instead of 3 ----------------
__global__ __launch_bounds__(256) void dl_pass1(
    const float4* __restrict__ bbox, const float* __restrict__ conf,
    const float4* __restrict__ gt,
    uint8_t* __restrict__ best_idx, uint32_t* __restrict__ negkey,
    unsigned long long* __restrict__ gt_part,
    uint32_t* __restrict__ hist_cnt, float* __restrict__ hist_sum,
    float* __restrict__ part_loc, float* __restrict__ part_fl, float* __restrict__ part_np) {
  const int img = blockIdx.y;
  const int bx  = blockIdx.x;
  const int t   = threadIdx.x;
  const int wave = t >> 6, lane = t & 63;
  const int a = bx * 256 + t;
  const int idx = img * A_N + a;

  __shared__ float4 sg2[2 * G_N];   // gt boxes doubled: index lane+j needs no &63 wrap
  __shared__ unsigned long long spart[4][G_N];
  __shared__ uint32_t hc[NBIN];
  __shared__ float    hs[NBIN];
  __shared__ float sl[4], sf[4], sn[4];

  for (int i = t; i < NBIN; i += 256) { hc[i] = 0u; hs[i] = 0.f; }
  if (t < G_N) {
    float4 q0 = gt[img * G_N + t];
    sg2[t] = q0;  sg2[t + G_N] = q0;
  }
  __syncthreads();

  float4 p = bbox[idx];
  float pa = __fmul_rn(__fsub_rn(p.z, p.x), __fsub_rn(p.w, p.y));
  float l = conf[idx];

  float posm = -1.f;
  uint32_t rowkey = 0u;                       // packed (ratio_bits | 63-g) row max
  uint32_t colkey = 0u;                       // rotating column-max register
  uint32_t tb = 63u - (uint32_t)lane;         // rotating row tie-break = 63-g, g=(lane+j)&63
  const int rotsrc = (lane + 1) & 63;         // pull from next lane after each iter
  const uint32_t lanecomp = 63u - (uint32_t)lane;  // column tie-break (smaller lane wins)

  #pragma unroll 8
  for (int j = 0; j < G_N; ++j) {
    float4 q = sg2[lane + j];                 // fixed addr reg + offset:j*16
    // exact f32 area, recomputed in VALU (identical bits to a precomputed copy)
    float qa = __fmul_rn(__fsub_rn(q.z, q.x), __fsub_rn(q.w, q.y));
    float ix1 = fmaxf(p.x, q.x), iy1 = fmaxf(p.y, q.y);
    float ix2 = fminf(p.z, q.z), iy2 = fminf(p.w, q.w);
    float iw = fmaxf(__fsub_rn(ix2, ix1), 0.f);
    float ih = fmaxf(__fsub_rn(iy2, iy1), 0.f);
    float inter = __fmul_rn(iw, ih);
    float den = __fadd_rn(__fsub_rn(__fadd_rn(pa, qa), inter), FEPS);  // exact numpy den
    // pos threshold EXACT: iou > 0.5 <=> sign(2*inter - den) > 0 (RN preserves sign)
    posm = fmaxf(posm, __fmaf_rn(2.f, inter, -den));
    // shared approx ratio (1-ulp rcp); near-tie flips are measure-zero on random data
    float ratio = inter * __builtin_amdgcn_rcpf(den);
    uint32_t base = __float_as_uint(ratio) & 0xFFFFFFC0u;
    rowkey = max(rowkey, base | tb);          // v_max_u32; smaller g wins ties
    colkey = max(colkey, base | lanecomp);
    colkey = __shfl(colkey, rotsrc);          // register now belongs to g+1
    tb = (tb - 1u) & 63u;                     // g+1 -> tie-break decrements (wraps 0->63)
  }

  const bool pos = posm > 0.f;
  const int bidx = 63 - (int)(rowkey & 63u);
  best_idx[idx] = (uint8_t)bidx;

  // ---- fused focal + negkey + DIoU (matched gt is already in LDS) ----
  float fl = focal_one(l, pos ? 1.0f : 0.0f);
  negkey[idx] = pos ? 0u : __float_as_uint(fl);  // fl > 0 strictly; 0 sentinel below all negatives
  float locv = pos ? diou_one(p, sg2[bidx]) : 0.0f;
  if (!pos) {
    uint32_t kb = __float_as_uint(fl);
    atomicAdd(&hc[kb >> SHB], 1u);       // 256 keys into 2048 bins: ~conflict-free
    atomicAdd(&hs[kb >> SHB], fl);
  }

  // lane l holds the wave's column max for gt l; build cross-block comparable u64 key
  uint32_t winlane = 63u - (colkey & 63u);
  uint32_t ganchor = (uint32_t)(bx * 256 + wave * 64) + winlane;
  unsigned long long wkey = ((unsigned long long)(colkey & 0xFFFFFFC0u) << 32)
                          | (unsigned)~ganchor;  // smaller global idx wins ties
  spart[wave][lane] = wkey;

  // per-wave partials
  float flp = pos ? fl : 0.0f;
  float np1 = pos ? 1.0f : 0.0f;
  float lv = locv;
  for (int o = 32; o; o >>= 1) {
    lv  += __shfl_down(lv, o);
    flp += __shfl_down(flp, o);
    np1 += __shfl_down(np1, o);
  }
  if (lane == 0) { sl[wave] = lv; sf[wave] = flp; sn[wave] = np1; }
  __syncthreads();

  // flush nonzero hist bins, gt partial, block partials
  for (int i = t; i < NBIN; i += 256) {
    uint32_t c = hc[i];
    if (c) {
      atomicAdd(&hist_cnt[img * NBIN + i], c);
      atomicAdd(&hist_sum[img * NBIN + i], hs[i]);
    }
  }
  if (t < G_N) {
    unsigned long long m = spart[0][t];
    if (spart[1][t] > m) m = spart[1][t];
    if (spart[2][t] > m) m = spart[2][t];
    if (spart[3][t] > m) m = spart[3][t];
    gt_part[(((size_t)(img << 8) | bx) << 6) | t] = m;  // coalesced 512B store
  }
  if (t == 0) {
    const int pi = img * 256 + bx;
    part_loc[pi] = sl[0] + sl[1] + sl[2] + sl[3];
    part_fl[pi]  = sf[0] + sf[1] + sf[2] + sf[3];
    part_np[pi]  = sn[0] + sn[1] + sn[2] + sn[3];  // integer-valued, exact
  }
}

// ---------------- K2: force+fixup + radix top-k. L2 = 8192 bins so the r3==cbin2
// shortcut almost always fires -> usually only ONE 256KB streaming pass ----------------
__global__ __launch_bounds__(1024) void dl_select(
    uint32_t* negkey,   // no __restrict__: read after in-kernel atomicExch fixup
    const unsigned long long* __restrict__ gt_part,
    const uint32_t* __restrict__ hist_cnt, const float* __restrict__ hist_sum,
    const float* __restrict__ part_loc, const float* __restrict__ part_fl,
    const float* __restrict__ part_np,
    const float4* __restrict__ bbox, const float* __restrict__ conf,
    const float4* __restrict__ gt, const uint8_t* __restrict__ best_idx,
    float* __restrict__ acc) {
  const int img = blockIdx.x;
  const int t = threadIdx.x;
  uint32_t* negk = negkey + (size_t)img * A_N;
  const uint4* k4 = (const uint4*)negk;
  const int N4 = A_N / 4;  // 16384

  __shared__ uint32_t cnt[NBIN];      // L1: bits[31:21]          8 KB
  __shared__ float    bsum[NBIN];     //                          8 KB
  __shared__ uint32_t hc2[NB2];       // L2: bits[20:8]          32 KB
  __shared__ float    hs2[NB2];       //                         32 KB
  __shared__ uint32_t cnt3[NB3];      // L3: bits[7:0]            1 KB
  __shared__ uint32_t chunks[1024];   // L2 scan chunk sums       4 KB
  __shared__ uint32_t pbase[64];
  __shared__ unsigned long long gred[16][G_N];                 //  8 KB
  __shared__ float s3[3][4];
  __shared__ float redf[16];
  __shared__ float np_sh, psum_sh, loc_sh, sstar_sh, sstar2_sh, negsum_sh;
  __shared__ float fix_l, fix_f, fix_n;
  __shared__ uint32_t bstar_sh, cstar_sh, b2_sh, c2_sh, j3_sh, c3_sh;

  // ---- region A: load L1 hist, zero L2/L3, stage gt_part, reduce block partials ----
  for (int i = t; i < NBIN; i += 1024) {
    cnt[i]  = hist_cnt[img * NBIN + i];
    bsum[i] = hist_sum[img * NBIN + i];
  }
  for (int i = t; i < NB2; i += 1024) { hc2[i] = 0u; hs2[i] = 0.f; }
  if (t < NB3) cnt3[t] = 0u;
  {
    const int g = t & 63, ch = t >> 6;   // 16 chunks x 64 gts
    unsigned long long m = 0ull;
    #pragma unroll 4
    for (int j = 0; j < 16; ++j) {
      unsigned long long v = gt_part[(((size_t)(img << 8) | (ch * 16 + j)) << 6) | g];
      if (v > m) m = v;
    }
    gred[ch][g] = m;
  }
  float lv = 0.f, fv = 0.f, nv = 0.f;
  if (t < 256) {
    lv = part_loc[img * 256 + t];
    fv = part_fl[img * 256 + t];
    nv = part_np[img * 256 + t];
  }
  for (int o = 32; o; o >>= 1) {
    lv += __shfl_down(lv, o);
    fv += __shfl_down(fv, o);
    nv += __shfl_down(nv, o);
  }
  if (t < 256 && (t & 63) == 0) { s3[0][t >> 6] = lv; s3[1][t >> 6] = fv; s3[2][t >> 6] = nv; }
  __syncthreads();

  // ---- region B (wave 0): per-gt final argmax + forced-positive fixup ----
  if (t < 64) {
    unsigned long long m = gred[0][t];
    #pragma unroll
    for (int c = 1; c < 16; ++c) if (gred[c][t] > m) m = gred[c][t];
    // all-zero column: ratio bits 0 -> max low-word = ~0 -> anchor 0 (numpy argmax)
    uint32_t a = ~(uint32_t)(m & 0xFFFFFFFFull);
    // dedupe multiple gts forcing the same anchor; skips already-positive anchors
    uint32_t old = atomicExch(&negk[a], 0u);
    float dl = 0.f, df = 0.f, dn = 0.f;
    if (old != 0u) {
      dn = 1.f;
      float fln = __uint_as_float(old);
      uint32_t bin = old >> SHB;
      atomicSub(&cnt[bin], 1u);          // remove from negative hist
      atomicAdd(&bsum[bin], -fln);
      const int ai = img * A_N + (int)a;
      df = focal_one(conf[ai], 1.0f);    // now a positive
      dl = diou_one(bbox[ai], gt[img * G_N + best_idx[ai]]);
    }
    for (int o = 32; o; o >>= 1) {
      dl += __shfl_down(dl, o);
      df += __shfl_down(df, o);
      dn += __shfl_down(dn, o);
    }
    if (t == 0) { fix_l = dl; fix_f = df; fix_n = dn; }
  }
  __syncthreads();

  if (t == 0) {
    loc_sh  = s3[0][0] + s3[0][1] + s3[0][2] + s3[0][3] + fix_l;
    psum_sh = s3[1][0] + s3[1][1] + s3[1][2] + s3[1][3] + fix_f;
    np_sh   = s3[2][0] + s3[2][1] + s3[2][2] + s3[2][3] + fix_n;
    negsum_sh = 0.f;
  }
  __syncthreads();

  const int np = (int)(np_sh + 0.5f);
  const int k = min(A_N - np, 3 * np);

  if (k > 0) {
    // ---- L1 scan (wave 0): threshold bin b*: C(>b*) < k <= C(>=b*) ----
    if (t < 64) {
      const int CH = NBIN / 64;
      const int lob = NBIN - CH * (t + 1);   // lane 0 owns the TOP chunk
      uint32_t csum = 0;
      for (int b = lob; b < lob + CH; ++b) csum += cnt[b];
      uint32_t pre = csum;
      for (int o = 1; o < 64; o <<= 1) { uint32_t u = __shfl_up(pre, o); if (t >= o) pre += u; }
      uint32_t run = pre - csum;
      for (int b = lob + CH - 1; b >= lob; --b) {
        uint32_t c = cnt[b];
        if (run < (uint32_t)k && run + c >= (uint32_t)k) { bstar_sh = (uint32_t)b; cstar_sh = run; }
        run += c;
      }
    }
    __syncthreads();
    const uint32_t bstar = bstar_sh;
    const uint32_t cbin = cnt[bstar];
    const uint32_t r = (uint32_t)k - cstar_sh;  // 1 <= r <= cbin

    // ---- Sstar = sum of keys in L1 bins > b* (all threads) ----
    float s = 0.f;
    for (int i = t; i < NBIN; i += 1024) if (i > (int)bstar) s += bsum[i];
    for (int o = 32; o; o >>= 1) s += __shfl_down(s, o);
    if ((t & 63) == 0) redf[t >> 6] = s;
    __syncthreads();
    if (t == 0) {
      float ss = 0.f;
      #pragma unroll
      for (int w = 0; w < 16; ++w) ss += redf[w];
      sstar_sh = ss;
    }
    __syncthreads();

    if (r == cbin) {
      if (t == 0) negsum_sh = sstar_sh + bsum[bstar];
    } else {
      // ---- streaming pass: L2 hist (8192 bins) of boundary-bin keys ----
      for (int i = t; i < N4; i += 1024) {
        uint4 v = k4[i];
        if (v.x != 0u && (v.x >> SHB) == bstar) { atomicAdd(&hc2[(v.x >> 8) & (NB2-1)], 1u); atomicAdd(&hs2[(v.x >> 8) & (NB2-1)], __uint_as_float(v.x)); }
        if (v.y != 0u && (v.y >> SHB) == bstar) { atomicAdd(&hc2[(v.y >> 8) & (NB2-1)], 1u); atomicAdd(&hs2[(v.y >> 8) & (NB2-1)], __uint_as_float(v.y)); }
        if (v.z != 0u && (v.z >> SHB) == bstar) { atomicAdd(&hc2[(v.z >> 8) & (NB2-1)], 1u); atomicAdd(&hs2[(v.z >> 8) & (NB2-1)], __uint_as_float(v.z)); }
        if (v.w != 0u && (v.w >> SHB) == bstar) { atomicAdd(&hc2[(v.w >> 8) & (NB2-1)], 1u); atomicAdd(&hs2[(v.w >> 8) & (NB2-1)], __uint_as_float(v.w)); }
      }
      __syncthreads();

      // ---- L2 scan, all 1024 threads: thread t owns 8 bins [NB2-8(t+1), NB2-8t) ----
      {
        const int cb = NB2 - 8 * (t + 1);
        uint32_t cs = 0;
        #pragma unroll
        for (int j = 0; j < 8; ++j) cs += hc2[cb + j];
        chunks[t] = cs;
      }
      __syncthreads();
      if (t < 64) {
        uint32_t s16 = 0;
        #pragma unroll 4
        for (int j = 0; j < 16; ++j) s16 += chunks[t * 16 + j];
        uint32_t pre = s16;
        for (int o = 1; o < 64; o <<= 1) { uint32_t u = __shfl_up(pre, o); if (t >= o) pre += u; }
        pbase[t] = pre - s16;   // keys in chunks before group t*16
      }
      __syncthreads();
      {
        uint32_t run = pbase[t >> 4];
        const int gb = (t >> 4) << 4;
        for (int j = gb; j < t; ++j) run += chunks[j];
        for (int b = NB2 - 8 * t - 1; b >= NB2 - 8 * (t + 1); --b) {
          uint32_t c = hc2[b];
          if (run < r && run + c >= r) { b2_sh = (uint32_t)b; c2_sh = run; }  // exactly one hit
          run += c;
        }
      }
      __syncthreads();
      const uint32_t b2 = b2_sh;
      const uint32_t cbin2 = hc2[b2];
      const uint32_t r3 = r - c2_sh;  // 1 <= r3 <= cbin2

      // ---- Sstar2 = sum of keys in L2 bins > b2* (all threads) ----
      float s2 = 0.f;
      for (int i = t; i < NB2; i += 1024) if (i > (int)b2) s2 += hs2[i];
      for (int o = 32; o; o >>= 1) s2 += __shfl_down(s2, o);
      if ((t & 63) == 0) redf[t >> 6] = s2;
      __syncthreads();
      if (t == 0) {
        float ss = 0.f;
        #pragma unroll
        for (int w = 0; w < 16; ++w) ss += redf[w];
        sstar2_sh = ss;
      }
      __syncthreads();

      if (r3 == cbin2) {
        if (t == 0) negsum_sh = sstar_sh + sstar2_sh + hs2[b2];
      } else {
        // ---- rare: L3 exact-value hist over bits[7:0] (top-24-bit filter) ----
        const uint32_t top24 = (bstar << 13) | b2;
        for (int i = t; i < N4; i += 1024) {
          uint4 v = k4[i];
          if (v.x != 0u && (v.x >> 8) == top24) atomicAdd(&cnt3[v.x & 255u], 1u);
          if (v.y != 0u && (v.y >> 8) == top24) atomicAdd(&cnt3[v.y & 255u], 1u);
          if (v.z != 0u && (v.z >> 8) == top24) atomicAdd(&cnt3[v.z & 255u], 1u);
          if (v.w != 0u && (v.w >> 8) == top24) atomicAdd(&cnt3[v.w & 255u], 1u);
        }
        __syncthreads();

        // ---- L3 scan (wave 0): exact value j*: C3(>j*) < r3 <= C3(>=j*) ----
        if (t < 64) {
          const int CH = NB3 / 64;  // 4
          const int lob = NB3 - CH * (t + 1);
          uint32_t csum = 0;
          for (int b = lob; b < lob + CH; ++b) csum += cnt3[b];
          uint32_t pre = csum;
          for (int o = 1; o < 64; o <<= 1) { uint32_t u = __shfl_up(pre, o); if (t >= o) pre += u; }
          uint32_t run = pre - csum;
          for (int b = lob + CH - 1; b >= lob; --b) {
            uint32_t c = cnt3[b];
            if (run < r3 && run + c >= r3) { j3_sh = (uint32_t)b; c3_sh = run; }
            run += c;
          }
        }
        __syncthreads();
        const uint32_t j3 = j3_sh;
        const uint32_t hibits = (bstar << SHB) | (b2 << 8);

        // ---- exact tail sum: values above j* + boundary copies of val(j*) ----
        float s3v = 0.f;
        if (t < NB3 && t > (int)j3 && cnt3[t]) {
          s3v = (float)cnt3[t] * __uint_as_float(hibits | (uint32_t)t);
        }
        for (int o = 32; o; o >>= 1) s3v += __shfl_down(s3v, o);
        if ((t & 63) == 0) redf[t >> 6] = s3v;
        __syncthreads();
        if (t == 0) {
          float ss = 0.f;
          #pragma unroll
          for (int w = 0; w < 16; ++w) ss += redf[w];
          negsum_sh = sstar_sh + sstar2_sh + ss
                    + (float)(int)(r3 - c3_sh) * __uint_as_float(hibits | j3);
        }
      }
    }
  }
  __syncthreads();
  if (t == 0) {
    acc[img] = loc_sh;
    acc[32 + img] = (float)np;
    acc[48 + img] = (psum_sh + negsum_sh) / fmaxf((float)(np + k), 1.0f);
  }
}

// ---------------- K3: final combine (kernel boundary = free device-wide release) ----------------
__global__ void dl_final(const float* __restrict__ acc, float* __restrict__ out) {
  if (threadIdx.x == 0 && blockIdx.x == 0) {
    float sl = 0.0f, sc = 0.0f, sn = 0.0f;
    for (int i = 0; i < B_N; ++i) {
      sl += acc[i];
      sc += acc[48 + i];
      sn += acc[32 + i];
    }
    float tp = fmaxf(sn, 1.0f);
    float al = sl / tp;
    float ac = sc / tp;
    out[0] = al + ac;
    out[1] = ac;
    out[2] = al;
  }
}

extern "C" void kernel_launch(void* const* d_in, const int* in_sizes, int n_in,
                              void* d_out, int out_size, void* d_ws, size_t ws_size,
                              hipStream_t stream) {
  (void)in_sizes; (void)n_in; (void)out_size; (void)ws_size;

  const float4* bbox = (const float4*)d_in[0];   // [B, A, 4] f32
  const float*  conf = (const float*)d_in[1];    // [B, A] f32
  const float4* gt   = (const float4*)d_in[2];   // [B, G, 4] f32
  float* out = (float*)d_out;

  char* ws = (char*)d_ws;
  uint32_t*           negkey   = (uint32_t*)(ws);                       // 4 MiB
  unsigned long long* gt_part  = (unsigned long long*)(ws + (4u << 20));// 2 MiB [16][256][64]
  uint8_t*            best_idx = (uint8_t*)(ws + (6u << 20));          // 1 MiB
  char* hb = ws + (7u << 20);
  uint32_t* hist_cnt = (uint32_t*)(hb);                                // 128 KiB [16][2048]
  float*    hist_sum = (float*)(hb + (size_t)B_N * NBIN * 4);          // 128 KiB (contiguous)
  char* tail = hb + 2 * (size_t)B_N * NBIN * 4;
  float* part_loc = (float*)(tail);                                    // 16 KiB
  float* part_fl  = (float*)(tail + 16384);
  float* part_np  = (float*)(tail + 32768);
  float* acc      = (float*)(tail + 49152);                            // 64 floats

  dl_init<<<64, 1024, 0, stream>>>(hist_cnt /* zeroes cnt+sum (contiguous) */);
  dl_pass1<<<dim3(A_N / 256, B_N), 256, 0, stream>>>(bbox, conf, gt, best_idx, negkey,
                                                     gt_part, hist_cnt, hist_sum,
                                                     part_loc, part_fl, part_np);
  dl_select<<<B_N, 1024, 0, stream>>>(negkey, gt_part, hist_cnt, hist_sum,
                                      part_loc, part_fl, part_np,
                                      bbox, conf, gt, best_idx, acc);
  dl_final<<<1, 64, 0, stream>>>(acc, out);
}